// Round 5
// baseline (360.102 us; speedup 1.0000x reference)
//
#include <hip/hip_runtime.h>
#include <hip/hip_bf16.h>

// MoE FFN: T=4096 tokens, H=I=1024, E=8 experts, top-2.
// INPUTS: float32 (proven on-device R4). OUTPUT: float32 (reference dtype).
// Pipeline: router -> bucket -> grouped GEMM1 (gate+up, f32->bf16 staging,
// fused SiLU) -> Hbuf(bf16) -> grouped GEMM2 (down) -> Acc(bf16) -> combine(f32).
// MFMA 16x16x32 bf16, 128x64 tiles, BK=32. Fallback fused path if ws < 33.75MB.

#define T_TOK 4096
#define HDIM  1024
#define NEXP  8
#define RROWS (T_TOK * 2)
#define MAXPE T_TOK

typedef unsigned short u16;
typedef short v8s __attribute__((ext_vector_type(8)));
typedef float v4f __attribute__((ext_vector_type(4)));

__device__ __forceinline__ float b2f(u16 u) {
    union { unsigned int i; float f; } v; v.i = ((unsigned int)u) << 16; return v.f;
}
__device__ __forceinline__ u16 f2b(float f) {
    union { float f; unsigned int i; } v; v.f = f;
    unsigned int x = v.i;
    return (u16)((x + 0x7FFFu + ((x >> 16) & 1u)) >> 16);
}
__device__ __forceinline__ unsigned int pack2(float a, float b) {
    return (unsigned int)f2b(a) | ((unsigned int)f2b(b) << 16);
}

// ---------------- router (f32 logits): softmax top-2 + renorm ----------------
__global__ void router_kernel(const float* __restrict__ logits,
                              int* __restrict__ ids, float* __restrict__ wts) {
    int t = blockIdx.x * blockDim.x + threadIdx.x;
    if (t >= T_TOK) return;
    float4 a = *(const float4*)(logits + t * NEXP);
    float4 b = *(const float4*)(logits + t * NEXP + 4);
    float l[NEXP] = {a.x, a.y, a.z, a.w, b.x, b.y, b.z, b.w};
    int i0 = 0;
#pragma unroll
    for (int i = 1; i < NEXP; i++) if (l[i] > l[i0]) i0 = i;
    int i1 = (i0 == 0) ? 1 : 0;
#pragma unroll
    for (int i = 0; i < NEXP; i++) if (i != i0 && l[i] > l[i1]) i1 = i;
    float w0 = 1.0f / (1.0f + expf(l[i1] - l[i0]));   // renorm cancels softmax Z
    ids[2 * t] = i0;     ids[2 * t + 1] = i1;
    wts[2 * t] = w0;     wts[2 * t + 1] = 1.0f - w0;
}

__global__ void bucket_kernel(const int* __restrict__ ids,
                              int* __restrict__ counts, int* __restrict__ rowbuf) {
    int r = blockIdx.x * blockDim.x + threadIdx.x;
    if (r >= RROWS) return;
    int e = ids[r];
    int pos = atomicAdd(&counts[e], 1);
    rowbuf[e * MAXPE + pos] = r;
}

// ---------------- grouped GEMM (path A) ----------------
// AF32: A f32 [.][1024]; else bf16(u16). B f32 [E][1024(k)][NB(n)].
// GATED: dual tile (gate n, up n+1024), epilogue silu(g)*u. C bf16 [RROWS][1024].
template<int GATED, int AF32>
__global__ __launch_bounds__(256)
void moe_gemm_kernel(const void* __restrict__ Av,
                     const float* __restrict__ B,
                     u16* __restrict__ C,
                     const int* __restrict__ counts,
                     const int* __restrict__ rowbuf,
                     int rowShift, int NB) {
    const int e   = blockIdx.z;
    const int cnt = counts[e];
    const int rt  = blockIdx.y;
    if (rt * 128 >= cnt) return;
    const int ct  = blockIdx.x;
    const int tid = threadIdx.x;

    __shared__ __align__(16) u16 sA[128 * 40];
    __shared__ __align__(16) u16 sB[(GATED ? 2 : 1) * 64 * 40];
    __shared__ int srid[128];

    if (tid < 128) {
        int idx = rt * 128 + tid;
        srid[tid] = (idx < cnt) ? rowbuf[e * MAXPE + idx] : -1;
    }
    __syncthreads();

    const int ar = tid >> 1, ac = (tid & 1) * 16;
    int arid = srid[ar];
    const float* aSrcF = 0; const u16* aSrcH = 0;
    if (arid >= 0) {
        if (AF32) aSrcF = (const float*)Av + (size_t)(arid >> rowShift) * HDIM + ac;
        else      aSrcH = (const u16*)Av + (size_t)(arid >> rowShift) * HDIM + ac;
    }
    u16* aDst = sA + ar * 40 + ac;

    const int kq2 = (tid >> 4) * 2, n4 = (tid & 15) * 4;
    const float* bSrcG = B + (size_t)e * 1024 * NB + (size_t)kq2 * NB + ct * 64 + n4;
    const float* bSrcU = bSrcG + 1024;

    const int lane = tid & 63, wave = tid >> 6;
    const int quad = lane >> 4, mr = lane & 15;

    const v4f zf = {0.f, 0.f, 0.f, 0.f};
    v4f accG[2][4], accU[2][4];
#pragma unroll
    for (int i = 0; i < 2; i++)
#pragma unroll
        for (int j = 0; j < 4; j++) { accG[i][j] = zf; accU[i][j] = zf; }

    for (int kk = 0; kk < HDIM / 32; kk++) {
        uint4 aw0 = make_uint4(0, 0, 0, 0), aw1 = make_uint4(0, 0, 0, 0);
        if (AF32) {
            if (aSrcF) {
                float4 f0 = *(const float4*)(aSrcF + kk * 32);
                float4 f1 = *(const float4*)(aSrcF + kk * 32 + 4);
                float4 f2 = *(const float4*)(aSrcF + kk * 32 + 8);
                float4 f3 = *(const float4*)(aSrcF + kk * 32 + 12);
                aw0 = make_uint4(pack2(f0.x, f0.y), pack2(f0.z, f0.w),
                                 pack2(f1.x, f1.y), pack2(f1.z, f1.w));
                aw1 = make_uint4(pack2(f2.x, f2.y), pack2(f2.z, f2.w),
                                 pack2(f3.x, f3.y), pack2(f3.z, f3.w));
            }
        } else {
            if (aSrcH) {
                aw0 = *(const uint4*)(aSrcH + kk * 32);
                aw1 = *(const uint4*)(aSrcH + kk * 32 + 8);
            }
        }
        const size_t bOff = (size_t)kk * 32 * NB;
        float4 g0 = *(const float4*)(bSrcG + bOff);
        float4 g1 = *(const float4*)(bSrcG + bOff + NB);
        float4 u0 = make_float4(0, 0, 0, 0), u1 = make_float4(0, 0, 0, 0);
        if (GATED) {
            u0 = *(const float4*)(bSrcU + bOff);
            u1 = *(const float4*)(bSrcU + bOff + NB);
        }

        __syncthreads();
        *(uint4*)aDst = aw0;
        *(uint4*)(aDst + 8) = aw1;
        {
            const float gx[4] = {g0.x, g0.y, g0.z, g0.w};
            const float gy[4] = {g1.x, g1.y, g1.z, g1.w};
#pragma unroll
            for (int j = 0; j < 4; j++)
                *(unsigned int*)&sB[(n4 + j) * 40 + kq2] = pack2(gx[j], gy[j]);
            if (GATED) {
                const float ux[4] = {u0.x, u0.y, u0.z, u0.w};
                const float uy[4] = {u1.x, u1.y, u1.z, u1.w};
#pragma unroll
                for (int j = 0; j < 4; j++)
                    *(unsigned int*)&sB[64 * 40 + (n4 + j) * 40 + kq2] = pack2(ux[j], uy[j]);
            }
        }
        __syncthreads();

        v8s af0 = *(const v8s*)(sA + (wave * 32 + mr) * 40 + quad * 8);
        v8s af1 = *(const v8s*)(sA + (wave * 32 + 16 + mr) * 40 + quad * 8);
#pragma unroll
        for (int nf = 0; nf < 4; nf++) {
            v8s bg = *(const v8s*)(sB + (nf * 16 + mr) * 40 + quad * 8);
            accG[0][nf] = __builtin_amdgcn_mfma_f32_16x16x32_bf16(af0, bg, accG[0][nf], 0, 0, 0);
            accG[1][nf] = __builtin_amdgcn_mfma_f32_16x16x32_bf16(af1, bg, accG[1][nf], 0, 0, 0);
            if (GATED) {
                v8s bu = *(const v8s*)(sB + 64 * 40 + (nf * 16 + mr) * 40 + quad * 8);
                accU[0][nf] = __builtin_amdgcn_mfma_f32_16x16x32_bf16(af0, bu, accU[0][nf], 0, 0, 0);
                accU[1][nf] = __builtin_amdgcn_mfma_f32_16x16x32_bf16(af1, bu, accU[1][nf], 0, 0, 0);
            }
        }
    }

    // C/D layout: col=lane&15, row=quad*4+reg [m89/m91]
#pragma unroll
    for (int mf = 0; mf < 2; mf++) {
#pragma unroll
        for (int reg = 0; reg < 4; reg++) {
            int rl = wave * 32 + mf * 16 + quad * 4 + reg;
            int grow = srid[rl];
            if (grow < 0) continue;
            size_t base = (size_t)grow * 1024 + ct * 64 + mr;
#pragma unroll
            for (int nf = 0; nf < 4; nf++) {
                float g = accG[mf][nf][reg];
                float val;
                if (GATED) {
                    float u = accU[mf][nf][reg];
                    val = (g / (1.0f + expf(-g))) * u;   // silu(g)*u
                } else {
                    val = g;
                }
                C[base + nf * 16] = f2b(val);
            }
        }
    }
}

// ---------------- combine: out(f32)[t] = w0*acc[2t] + w1*acc[2t+1] ----------------
__global__ void combine_kernel(const u16* __restrict__ accb,
                               const float* __restrict__ wts,
                               float* __restrict__ out) {
    int g = blockIdx.x * blockDim.x + threadIdx.x;
    int t = g >> 8;
    int c = (g & 255) * 4;
    float w0 = wts[2 * t], w1 = wts[2 * t + 1];
    ushort4 a = *(const ushort4*)(accb + (size_t)(2 * t) * 1024 + c);
    ushort4 b = *(const ushort4*)(accb + (size_t)(2 * t + 1) * 1024 + c);
    float4 o;
    o.x = w0 * b2f(a.x) + w1 * b2f(b.x);
    o.y = w0 * b2f(a.y) + w1 * b2f(b.y);
    o.z = w0 * b2f(a.z) + w1 * b2f(b.z);
    o.w = w0 * b2f(a.w) + w1 * b2f(b.w);
    *(float4*)(out + (size_t)t * 1024 + c) = o;
}

// ---------------- fused fallback (path B): f32 in, f32 atomic out ----------------
#define HSTR 1032
__global__ __launch_bounds__(256)
void fused_moe_kernel(const float* __restrict__ X,
                      const float* __restrict__ WU,
                      const float* __restrict__ WD,
                      const int* __restrict__ counts,
                      const int* __restrict__ rowbuf,
                      const float* __restrict__ wts,
                      float* __restrict__ out) {
    extern __shared__ __align__(16) u16 lds[];
    u16* hT = lds;
    u16* sA = lds + 64 * HSTR;
    u16* sW = sA + 64 * 40;
    __shared__ int srid[64];

    const int e   = blockIdx.y;
    const int cnt = counts[e];
    const int rt  = blockIdx.x;
    if (rt * 64 >= cnt) return;
    const int tid = threadIdx.x;

    if (tid < 64) {
        int idx = rt * 64 + tid;
        srid[tid] = (idx < cnt) ? rowbuf[e * MAXPE + idx] : -1;
    }
    __syncthreads();

    const int lane = tid & 63, wave = tid >> 6;
    const int quad = lane >> 4, mr = lane & 15;
    const int ar = tid >> 2, ac = (tid & 3) * 8;
    int arid = srid[ar];
    const float* aSrc = (arid >= 0) ? (X + (size_t)(arid >> 1) * HDIM + ac) : (const float*)0;
    const int kq2 = (tid >> 4) * 2, n4 = (tid & 15) * 4;
    const v4f zf = {0.f, 0.f, 0.f, 0.f};

    for (int nc = 0; nc < 16; nc++) {
        v4f accG[4], accU[4];
#pragma unroll
        for (int j = 0; j < 4; j++) { accG[j] = zf; accU[j] = zf; }
        const float* wG = WU + (size_t)e * 1024 * 2048 + (size_t)kq2 * 2048 + nc * 64 + n4;
        const float* wU = wG + 1024;

        for (int kk = 0; kk < 32; kk++) {
            uint4 aw = make_uint4(0, 0, 0, 0);
            if (aSrc) {
                float4 f0 = *(const float4*)(aSrc + kk * 32);
                float4 f1 = *(const float4*)(aSrc + kk * 32 + 4);
                aw = make_uint4(pack2(f0.x, f0.y), pack2(f0.z, f0.w),
                                pack2(f1.x, f1.y), pack2(f1.z, f1.w));
            }
            const size_t wOff = (size_t)kk * 32 * 2048;
            float4 g0 = *(const float4*)(wG + wOff);
            float4 g1 = *(const float4*)(wG + wOff + 2048);
            float4 u0 = *(const float4*)(wU + wOff);
            float4 u1 = *(const float4*)(wU + wOff + 2048);

            __syncthreads();
            *(uint4*)(sA + ar * 40 + ac) = aw;
            {
                const float gx[4] = {g0.x, g0.y, g0.z, g0.w};
                const float gy[4] = {g1.x, g1.y, g1.z, g1.w};
                const float ux[4] = {u0.x, u0.y, u0.z, u0.w};
                const float uy[4] = {u1.x, u1.y, u1.z, u1.w};
#pragma unroll
                for (int j = 0; j < 4; j++) {
                    *(unsigned int*)&sW[(n4 + j) * 40 + kq2] = pack2(gx[j], gy[j]);
                    *(unsigned int*)&sW[64 * 40 + (n4 + j) * 40 + kq2] = pack2(ux[j], uy[j]);
                }
            }
            __syncthreads();

            v8s af = *(const v8s*)(sA + (wave * 16 + mr) * 40 + quad * 8);
#pragma unroll
            for (int nf = 0; nf < 4; nf++) {
                v8s bg = *(const v8s*)(sW + (nf * 16 + mr) * 40 + quad * 8);
                accG[nf] = __builtin_amdgcn_mfma_f32_16x16x32_bf16(af, bg, accG[nf], 0, 0, 0);
                v8s bu = *(const v8s*)(sW + 64 * 40 + (nf * 16 + mr) * 40 + quad * 8);
                accU[nf] = __builtin_amdgcn_mfma_f32_16x16x32_bf16(af, bu, accU[nf], 0, 0, 0);
            }
        }
#pragma unroll
        for (int reg = 0; reg < 4; reg++) {
            int row = wave * 16 + quad * 4 + reg;
#pragma unroll
            for (int nf = 0; nf < 4; nf++) {
                float g = accG[nf][reg], u = accU[nf][reg];
                hT[row * HSTR + nc * 64 + nf * 16 + mr] = f2b((g / (1.0f + expf(-g))) * u);
            }
        }
    }
    __syncthreads();

    for (int ct = 0; ct < 16; ct++) {
        v4f acc[4];
#pragma unroll
        for (int j = 0; j < 4; j++) acc[j] = zf;
        const float* w2 = WD + (size_t)e * 1024 * 1024 + (size_t)kq2 * 1024 + ct * 64 + n4;

        for (int kk = 0; kk < 32; kk++) {
            const size_t wOff = (size_t)kk * 32 * 1024;
            float4 g0 = *(const float4*)(w2 + wOff);
            float4 g1 = *(const float4*)(w2 + wOff + 1024);

            __syncthreads();
            {
                const float gx[4] = {g0.x, g0.y, g0.z, g0.w};
                const float gy[4] = {g1.x, g1.y, g1.z, g1.w};
#pragma unroll
                for (int j = 0; j < 4; j++)
                    *(unsigned int*)&sW[(n4 + j) * 40 + kq2] = pack2(gx[j], gy[j]);
            }
            __syncthreads();

            v8s af = *(const v8s*)(hT + (wave * 16 + mr) * HSTR + kk * 32 + quad * 8);
#pragma unroll
            for (int nf = 0; nf < 4; nf++) {
                v8s bw = *(const v8s*)(sW + (nf * 16 + mr) * 40 + quad * 8);
                acc[nf] = __builtin_amdgcn_mfma_f32_16x16x32_bf16(af, bw, acc[nf], 0, 0, 0);
            }
        }
#pragma unroll
        for (int reg = 0; reg < 4; reg++) {
            int rl = wave * 16 + quad * 4 + reg;
            int grow = srid[rl];
            if (grow < 0) continue;
            float w = wts[grow];
            size_t base = (size_t)(grow >> 1) * 1024 + ct * 64 + mr;
#pragma unroll
            for (int nf = 0; nf < 4; nf++)
                atomicAdd(&out[base + nf * 16], w * acc[nf][reg]);
        }
    }
}

extern "C" void kernel_launch(void* const* d_in, const int* in_sizes, int n_in,
                              void* d_out, int out_size, void* d_ws, size_t ws_size,
                              hipStream_t stream) {
    // Defensive remap by element count (documented order: X, RL, WU, WD, topk).
    const float *X = 0, *RL = 0, *WU = 0, *WD = 0;
    for (int i = 0; i < n_in; i++) {
        switch (in_sizes[i]) {
            case T_TOK * HDIM:        X  = (const float*)d_in[i]; break;   // 4.19M
            case T_TOK * NEXP:        RL = (const float*)d_in[i]; break;   // 32768
            case NEXP * HDIM * 2048:  WU = (const float*)d_in[i]; break;   // 16.8M
            case NEXP * HDIM * 1024:  WD = (const float*)d_in[i]; break;   // 8.39M
            default: break;                                                // topk
        }
    }
    if (!X)  X  = (const float*)d_in[0];
    if (!RL) RL = (const float*)d_in[1];
    if (!WU) WU = (const float*)d_in[2];
    if (!WD) WD = (const float*)d_in[3];
    float* OUT = (float*)d_out;

    char* ws = (char*)d_ws;
    int*   ids    = (int*)(ws + 0);
    float* wts    = (float*)(ws + 32768);
    int*   counts = (int*)(ws + 65536);
    int*   rowbuf = (int*)(ws + 65792);          // ends at 196864
    u16* Hbuf = (u16*)(ws + 196864);             // 16 MB (path A)
    u16* Acc  = (u16*)(ws + 196864 + 16777216);  // 16 MB (path A)
    const size_t needA = 196864 + 2 * 16777216ull;   // 33.75 MB

    hipMemsetAsync(counts, 0, NEXP * sizeof(int), stream);
    router_kernel<<<T_TOK / 256, 256, 0, stream>>>(RL, ids, wts);
    bucket_kernel<<<RROWS / 256, 256, 0, stream>>>(ids, counts, rowbuf);

    if (ws_size >= needA) {
        moe_gemm_kernel<1, 1><<<dim3(16, 32, NEXP), 256, 0, stream>>>(
            (const void*)X, WU, Hbuf, counts, rowbuf, 1, 2048);
        moe_gemm_kernel<0, 0><<<dim3(16, 32, NEXP), 256, 0, stream>>>(
            (const void*)Hbuf, WD, Acc, counts, rowbuf, 0, 1024);
        combine_kernel<<<T_TOK, 256, 0, stream>>>(Acc, wts, OUT);
    } else {
        hipFuncSetAttribute((const void*)fused_moe_kernel,
                            hipFuncAttributeMaxDynamicSharedMemorySize, 147456);
        hipMemsetAsync(d_out, 0, (size_t)T_TOK * HDIM * sizeof(float), stream);
        fused_moe_kernel<<<dim3(64, NEXP), 256, 147456, stream>>>(
            X, WU, WD, counts, rowbuf, wts, OUT);
    }
}

// Round 6
// 296.269 us; speedup vs baseline: 1.2155x; 1.2155x over previous
//
#include <hip/hip_runtime.h>
#include <hip/hip_bf16.h>

// MoE FFN: T=4096, H=I=1024, E=8, top-2. Inputs f32, output f32.
// Fast path (ws>=72.2MB): router -> bucket -> cvtX/cvtW (bf16, W transposed
// to [e][n][k]) -> GEMM1 (gate+up+SiLU, global_load_lds staging, XOR-swizzle)
// -> Hbuf(bf16) -> GEMM2 (down, fused weighted atomic combine into out).
// Fallback (ws>=33.75MB): R5 proven 2-pass f32-staging path.

#define T_TOK 4096
#define HDIM  1024
#define NEXP  8
#define RROWS (T_TOK * 2)
#define MAXPE T_TOK

typedef unsigned short u16;
typedef short v8s __attribute__((ext_vector_type(8)));
typedef float v4f __attribute__((ext_vector_type(4)));
typedef __attribute__((address_space(3))) unsigned int as3_u32;
typedef const __attribute__((address_space(1))) unsigned int as1_u32c;

__device__ __forceinline__ float b2f(u16 u) {
    union { unsigned int i; float f; } v; v.i = ((unsigned int)u) << 16; return v.f;
}
__device__ __forceinline__ u16 f2b(float f) {
    union { float f; unsigned int i; } v; v.f = f;
    unsigned int x = v.i;
    return (u16)((x + 0x7FFFu + ((x >> 16) & 1u)) >> 16);
}
__device__ __forceinline__ unsigned int pack2(float a, float b) {
    return (unsigned int)f2b(a) | ((unsigned int)f2b(b) << 16);
}
__device__ __forceinline__ void stage16(const u16* g, u16* l) {
    __builtin_amdgcn_global_load_lds((as1_u32c*)g, (as3_u32*)l, 16, 0, 0);
}

// ---------------- router ----------------
__global__ void router_kernel(const float* __restrict__ logits,
                              int* __restrict__ ids, float* __restrict__ wts) {
    int t = blockIdx.x * blockDim.x + threadIdx.x;
    if (t >= T_TOK) return;
    float4 a = *(const float4*)(logits + t * NEXP);
    float4 b = *(const float4*)(logits + t * NEXP + 4);
    float l[NEXP] = {a.x, a.y, a.z, a.w, b.x, b.y, b.z, b.w};
    int i0 = 0;
#pragma unroll
    for (int i = 1; i < NEXP; i++) if (l[i] > l[i0]) i0 = i;
    int i1 = (i0 == 0) ? 1 : 0;
#pragma unroll
    for (int i = 0; i < NEXP; i++) if (i != i0 && l[i] > l[i1]) i1 = i;
    float w0 = 1.0f / (1.0f + expf(l[i1] - l[i0]));
    ids[2 * t] = i0;     ids[2 * t + 1] = i1;
    wts[2 * t] = w0;     wts[2 * t + 1] = 1.0f - w0;
}

__global__ void bucket_kernel(const int* __restrict__ ids,
                              int* __restrict__ counts, int* __restrict__ rowbuf) {
    int r = blockIdx.x * blockDim.x + threadIdx.x;
    if (r >= RROWS) return;
    int e = ids[r];
    int pos = atomicAdd(&counts[e], 1);
    rowbuf[e * MAXPE + pos] = r;
}

// ---------------- converts ----------------
__global__ void cvtX_kernel(const float* __restrict__ X, u16* __restrict__ Xb) {
    int i = (blockIdx.x * 256 + threadIdx.x) * 4;
    float4 f = *(const float4*)(X + i);
    uint2 o; o.x = pack2(f.x, f.y); o.y = pack2(f.z, f.w);
    *(uint2*)(Xb + i) = o;
}

// W[e][1024k][N] f32 -> Wt[e][N][1024k] bf16
__global__ void cvtW_kernel(const float* __restrict__ W, u16* __restrict__ Wt, int N) {
    __shared__ __align__(16) u16 tile[64 * 72];
    int e = blockIdx.z;
    int n0 = blockIdx.x * 64, k0 = blockIdx.y * 64;
    const float* Wb = W + (size_t)e * 1024 * N;
    u16* Wtb = Wt + (size_t)e * N * 1024;
    int r = threadIdx.x >> 4, c4 = (threadIdx.x & 15) * 4;
#pragma unroll
    for (int j = 0; j < 4; j++) {
        int k = r + j * 16;
        float4 f = *(const float4*)(Wb + (size_t)(k0 + k) * N + n0 + c4);
        tile[(c4 + 0) * 72 + k] = f2b(f.x);
        tile[(c4 + 1) * 72 + k] = f2b(f.y);
        tile[(c4 + 2) * 72 + k] = f2b(f.z);
        tile[(c4 + 3) * 72 + k] = f2b(f.w);
    }
    __syncthreads();
    int n = threadIdx.x >> 2, kc = (threadIdx.x & 3) * 16;
    uint4 v0 = *(const uint4*)&tile[n * 72 + kc];
    uint4 v1 = *(const uint4*)&tile[n * 72 + kc + 8];
    u16* dst = Wtb + (size_t)(n0 + n) * 1024 + k0 + kc;
    *(uint4*)dst = v0;
    *(uint4*)(dst + 8) = v1;
}

// ---------------- m97-style grouped GEMM, global_load_lds + XOR swizzle ----------------
// PHASE 1: A=Xb[4096][1024] (row=grow>>1), B=WtU[e][2048][1024]; dual 64-col
//          gate/up tile; epilogue silu*u -> Hbuf bf16. grid (16,32,8).
// PHASE 2: A=Hbuf[8192][1024] (row=grow), B=WtD[e][1024][1024]; 128-col tile;
//          epilogue atomicAdd(out[t], w*val). grid (8,32,8).
template<int PHASE>
__global__ __launch_bounds__(256)
void mfma_gemm(const u16* __restrict__ A, const u16* __restrict__ Bt,
               u16* __restrict__ H, float* __restrict__ OUT,
               const int* __restrict__ counts, const int* __restrict__ rowbuf,
               const float* __restrict__ wts) {
    const int e = blockIdx.z, rt = blockIdx.y, ct = blockIdx.x;
    const int cnt = counts[e];
    if (rt * 128 >= cnt) return;
    const int tid = threadIdx.x;
    const int lane = tid & 63, wave = tid >> 6;

    __shared__ __align__(16) u16 sA[128 * 64];   // [row][k], NO pad (global_load_lds)
    __shared__ __align__(16) u16 sB[128 * 64];   // [n][k]
    __shared__ int srid[128];

    if (tid < 128) {
        int idx = rt * 128 + tid;
        srid[tid] = (idx < cnt) ? rowbuf[e * MAXPE + idx] : -1;
    }
    __syncthreads();

    // staging: region p (p=0..3) covers tile rows R0=(p*4+wave)*8 .. +8.
    // lane l: row R0+(l>>3); fetches global chunk ((l&7)^(l>>3)) into slot (l&7).
    const int lrow = lane >> 3;
    const int lchunk = (lane & 7) ^ lrow;
    const u16* aPtr[4]; const u16* bPtr[4];
    u16 *aDst[4], *bDst[4];
#pragma unroll
    for (int p = 0; p < 4; p++) {
        int region = p * 4 + wave;
        int r = region * 8 + lrow;
        int rid = srid[r];
        int arow = (rid < 0) ? 0 : (PHASE == 1 ? (rid >> 1) : rid);
        aPtr[p] = A + (size_t)arow * 1024 + lchunk * 8;
        aDst[p] = sA + region * 512 + lane * 8;
        int n;
        if (PHASE == 1) n = (r < 64) ? (ct * 64 + r) : (1024 + ct * 64 + (r - 64));
        else            n = ct * 128 + r;
        bPtr[p] = Bt + (size_t)e * (PHASE == 1 ? 2048 : 1024) * 1024
                     + (size_t)n * 1024 + lchunk * 8;
        bDst[p] = sB + region * 512 + lane * 8;
    }

    const int quad = lane >> 4, mr = lane & 15;
    const int swA = mr & 7;          // row&7 == mr&7 for all fragment rows
    const v4f zf = {0.f, 0.f, 0.f, 0.f};
    v4f acc[2][8];
#pragma unroll
    for (int i = 0; i < 2; i++)
#pragma unroll
        for (int j = 0; j < 8; j++) acc[i][j] = zf;

    for (int kk = 0; kk < 16; kk++) {            // BK=64
        __syncthreads();                         // prev tile consumed
#pragma unroll
        for (int p = 0; p < 4; p++) {
            stage16(aPtr[p] + kk * 64, aDst[p]);
            stage16(bPtr[p] + kk * 64, bDst[p]);
        }
        __syncthreads();                         // loads landed (vmcnt drained)
#pragma unroll
        for (int kh = 0; kh < 2; kh++) {
            const int c = kh * 4 + quad;
            v8s a0 = *(const v8s*)(sA + (wave * 32 + mr) * 64 + ((c ^ swA) * 8));
            v8s a1 = *(const v8s*)(sA + (wave * 32 + 16 + mr) * 64 + ((c ^ swA) * 8));
#pragma unroll
            for (int nf = 0; nf < 8; nf++) {
                v8s b = *(const v8s*)(sB + (nf * 16 + mr) * 64 + ((c ^ swA) * 8));
                acc[0][nf] = __builtin_amdgcn_mfma_f32_16x16x32_bf16(a0, b, acc[0][nf], 0, 0, 0);
                acc[1][nf] = __builtin_amdgcn_mfma_f32_16x16x32_bf16(a1, b, acc[1][nf], 0, 0, 0);
            }
        }
    }

    // C/D layout: col = lane&15, row = quad*4+reg  [m89/m91, R5-validated]
#pragma unroll
    for (int mf = 0; mf < 2; mf++) {
#pragma unroll
        for (int reg = 0; reg < 4; reg++) {
            int rl = wave * 32 + mf * 16 + quad * 4 + reg;
            int grow = srid[rl];
            if (grow < 0) continue;
            if (PHASE == 1) {
                size_t base = (size_t)grow * 1024 + ct * 64 + mr;
#pragma unroll
                for (int nf = 0; nf < 4; nf++) {
                    float g = acc[mf][nf][reg], u = acc[mf][nf + 4][reg];
                    H[base + nf * 16] = f2b((g / (1.0f + expf(-g))) * u);
                }
            } else {
                float w = wts[grow];
                size_t base = (size_t)(grow >> 1) * 1024 + ct * 128 + mr;
#pragma unroll
                for (int nf = 0; nf < 8; nf++)
                    atomicAdd(&OUT[base + nf * 16], w * acc[mf][nf][reg]);
            }
        }
    }
}

// ================= R5 fallback path (proven, f32 in-GEMM staging) =================
template<int GATED, int AF32>
__global__ __launch_bounds__(256)
void moe_gemm_kernel(const void* __restrict__ Av,
                     const float* __restrict__ B,
                     u16* __restrict__ C,
                     const int* __restrict__ counts,
                     const int* __restrict__ rowbuf,
                     int rowShift, int NB) {
    const int e   = blockIdx.z;
    const int cnt = counts[e];
    const int rt  = blockIdx.y;
    if (rt * 128 >= cnt) return;
    const int ct  = blockIdx.x;
    const int tid = threadIdx.x;

    __shared__ __align__(16) u16 sA[128 * 40];
    __shared__ __align__(16) u16 sB[(GATED ? 2 : 1) * 64 * 40];
    __shared__ int srid[128];

    if (tid < 128) {
        int idx = rt * 128 + tid;
        srid[tid] = (idx < cnt) ? rowbuf[e * MAXPE + idx] : -1;
    }
    __syncthreads();

    const int ar = tid >> 1, ac = (tid & 1) * 16;
    int arid = srid[ar];
    const float* aSrcF = 0; const u16* aSrcH = 0;
    if (arid >= 0) {
        if (AF32) aSrcF = (const float*)Av + (size_t)(arid >> rowShift) * HDIM + ac;
        else      aSrcH = (const u16*)Av + (size_t)(arid >> rowShift) * HDIM + ac;
    }
    u16* aDst = sA + ar * 40 + ac;

    const int kq2 = (tid >> 4) * 2, n4 = (tid & 15) * 4;
    const float* bSrcG = B + (size_t)e * 1024 * NB + (size_t)kq2 * NB + ct * 64 + n4;
    const float* bSrcU = bSrcG + 1024;

    const int lane = tid & 63, wave = tid >> 6;
    const int quad = lane >> 4, mr = lane & 15;

    const v4f zf = {0.f, 0.f, 0.f, 0.f};
    v4f accG[2][4], accU[2][4];
#pragma unroll
    for (int i = 0; i < 2; i++)
#pragma unroll
        for (int j = 0; j < 4; j++) { accG[i][j] = zf; accU[i][j] = zf; }

    for (int kk = 0; kk < HDIM / 32; kk++) {
        uint4 aw0 = make_uint4(0, 0, 0, 0), aw1 = make_uint4(0, 0, 0, 0);
        if (AF32) {
            if (aSrcF) {
                float4 f0 = *(const float4*)(aSrcF + kk * 32);
                float4 f1 = *(const float4*)(aSrcF + kk * 32 + 4);
                float4 f2 = *(const float4*)(aSrcF + kk * 32 + 8);
                float4 f3 = *(const float4*)(aSrcF + kk * 32 + 12);
                aw0 = make_uint4(pack2(f0.x, f0.y), pack2(f0.z, f0.w),
                                 pack2(f1.x, f1.y), pack2(f1.z, f1.w));
                aw1 = make_uint4(pack2(f2.x, f2.y), pack2(f2.z, f2.w),
                                 pack2(f3.x, f3.y), pack2(f3.z, f3.w));
            }
        } else {
            if (aSrcH) {
                aw0 = *(const uint4*)(aSrcH + kk * 32);
                aw1 = *(const uint4*)(aSrcH + kk * 32 + 8);
            }
        }
        const size_t bOff = (size_t)kk * 32 * NB;
        float4 g0 = *(const float4*)(bSrcG + bOff);
        float4 g1 = *(const float4*)(bSrcG + bOff + NB);
        float4 u0 = make_float4(0, 0, 0, 0), u1 = make_float4(0, 0, 0, 0);
        if (GATED) {
            u0 = *(const float4*)(bSrcU + bOff);
            u1 = *(const float4*)(bSrcU + bOff + NB);
        }

        __syncthreads();
        *(uint4*)aDst = aw0;
        *(uint4*)(aDst + 8) = aw1;
        {
            const float gx[4] = {g0.x, g0.y, g0.z, g0.w};
            const float gy[4] = {g1.x, g1.y, g1.z, g1.w};
#pragma unroll
            for (int j = 0; j < 4; j++)
                *(unsigned int*)&sB[(n4 + j) * 40 + kq2] = pack2(gx[j], gy[j]);
            if (GATED) {
                const float ux[4] = {u0.x, u0.y, u0.z, u0.w};
                const float uy[4] = {u1.x, u1.y, u1.z, u1.w};
#pragma unroll
                for (int j = 0; j < 4; j++)
                    *(unsigned int*)&sB[64 * 40 + (n4 + j) * 40 + kq2] = pack2(ux[j], uy[j]);
            }
        }
        __syncthreads();

        v8s af0 = *(const v8s*)(sA + (wave * 32 + mr) * 40 + quad * 8);
        v8s af1 = *(const v8s*)(sA + (wave * 32 + 16 + mr) * 40 + quad * 8);
#pragma unroll
        for (int nf = 0; nf < 4; nf++) {
            v8s bg = *(const v8s*)(sB + (nf * 16 + mr) * 40 + quad * 8);
            accG[0][nf] = __builtin_amdgcn_mfma_f32_16x16x32_bf16(af0, bg, accG[0][nf], 0, 0, 0);
            accG[1][nf] = __builtin_amdgcn_mfma_f32_16x16x32_bf16(af1, bg, accG[1][nf], 0, 0, 0);
            if (GATED) {
                v8s bu = *(const v8s*)(sB + 64 * 40 + (nf * 16 + mr) * 40 + quad * 8);
                accU[0][nf] = __builtin_amdgcn_mfma_f32_16x16x32_bf16(af0, bu, accU[0][nf], 0, 0, 0);
                accU[1][nf] = __builtin_amdgcn_mfma_f32_16x16x32_bf16(af1, bu, accU[1][nf], 0, 0, 0);
            }
        }
    }

#pragma unroll
    for (int mf = 0; mf < 2; mf++) {
#pragma unroll
        for (int reg = 0; reg < 4; reg++) {
            int rl = wave * 32 + mf * 16 + quad * 4 + reg;
            int grow = srid[rl];
            if (grow < 0) continue;
            size_t base = (size_t)grow * 1024 + ct * 64 + mr;
#pragma unroll
            for (int nf = 0; nf < 4; nf++) {
                float g = accG[mf][nf][reg];
                float val;
                if (GATED) {
                    float u = accU[mf][nf][reg];
                    val = (g / (1.0f + expf(-g))) * u;
                } else {
                    val = g;
                }
                C[base + nf * 16] = f2b(val);
            }
        }
    }
}

__global__ void combine_kernel(const u16* __restrict__ accb,
                               const float* __restrict__ wts,
                               float* __restrict__ out) {
    int g = blockIdx.x * blockDim.x + threadIdx.x;
    int t = g >> 8;
    int c = (g & 255) * 4;
    float w0 = wts[2 * t], w1 = wts[2 * t + 1];
    ushort4 a = *(const ushort4*)(accb + (size_t)(2 * t) * 1024 + c);
    ushort4 b = *(const ushort4*)(accb + (size_t)(2 * t + 1) * 1024 + c);
    float4 o;
    o.x = w0 * b2f(a.x) + w1 * b2f(b.x);
    o.y = w0 * b2f(a.y) + w1 * b2f(b.y);
    o.z = w0 * b2f(a.z) + w1 * b2f(b.z);
    o.w = w0 * b2f(a.w) + w1 * b2f(b.w);
    *(float4*)(out + (size_t)t * 1024 + c) = o;
}

extern "C" void kernel_launch(void* const* d_in, const int* in_sizes, int n_in,
                              void* d_out, int out_size, void* d_ws, size_t ws_size,
                              hipStream_t stream) {
    const float *X = 0, *RL = 0, *WU = 0, *WD = 0;
    for (int i = 0; i < n_in; i++) {
        switch (in_sizes[i]) {
            case T_TOK * HDIM:        X  = (const float*)d_in[i]; break;
            case T_TOK * NEXP:        RL = (const float*)d_in[i]; break;
            case NEXP * HDIM * 2048:  WU = (const float*)d_in[i]; break;
            case NEXP * HDIM * 1024:  WD = (const float*)d_in[i]; break;
            default: break;
        }
    }
    if (!X)  X  = (const float*)d_in[0];
    if (!RL) RL = (const float*)d_in[1];
    if (!WU) WU = (const float*)d_in[2];
    if (!WD) WD = (const float*)d_in[3];
    float* OUT = (float*)d_out;

    char* ws = (char*)d_ws;
    int*   ids    = (int*)(ws + 0);
    float* wts    = (float*)(ws + 32768);
    int*   counts = (int*)(ws + 65536);
    int*   rowbuf = (int*)(ws + 65792);               // ends 196864
    // fast-path layout
    u16* Xb   = (u16*)(ws + 196864);                  // 8 MB   -> 8585472
    u16* WtU  = (u16*)(ws + 8585472);                 // 32 MB  -> 42139904
    u16* WtD  = (u16*)(ws + 42139904);                // 16 MB  -> 58917120
    u16* HbufF= (u16*)(ws + 58917120);                // 16 MB  -> 75694336
    const size_t needFast = 75694336ull;
    // fallback layout (R5)
    u16* Hbuf = (u16*)(ws + 196864);
    u16* Acc  = (u16*)(ws + 196864 + 16777216);
    const size_t needA = 196864 + 2 * 16777216ull;

    hipMemsetAsync(counts, 0, NEXP * sizeof(int), stream);
    router_kernel<<<T_TOK / 256, 256, 0, stream>>>(RL, ids, wts);
    bucket_kernel<<<RROWS / 256, 256, 0, stream>>>(ids, counts, rowbuf);

    if (ws_size >= needFast) {
        hipMemsetAsync(d_out, 0, (size_t)out_size * sizeof(float), stream);
        cvtX_kernel<<<T_TOK * HDIM / 1024, 256, 0, stream>>>(X, Xb);
        cvtW_kernel<<<dim3(32, 16, NEXP), 256, 0, stream>>>(WU, WtU, 2048);
        cvtW_kernel<<<dim3(16, 16, NEXP), 256, 0, stream>>>(WD, WtD, 1024);
        mfma_gemm<1><<<dim3(16, 32, NEXP), 256, 0, stream>>>(
            Xb, WtU, HbufF, OUT, counts, rowbuf, wts);
        mfma_gemm<2><<<dim3(8, 32, NEXP), 256, 0, stream>>>(
            HbufF, WtD, HbufF, OUT, counts, rowbuf, wts);
    } else {
        moe_gemm_kernel<1, 1><<<dim3(16, 32, NEXP), 256, 0, stream>>>(
            (const void*)X, WU, Hbuf, counts, rowbuf, 1, 2048);
        moe_gemm_kernel<0, 0><<<dim3(16, 32, NEXP), 256, 0, stream>>>(
            (const void*)Hbuf, WD, Acc, counts, rowbuf, 0, 1024);
        combine_kernel<<<T_TOK, 256, 0, stream>>>(Acc, wts, OUT);
    }
}

// Round 7
// 285.620 us; speedup vs baseline: 1.2608x; 1.0373x over previous
//
#include <hip/hip_runtime.h>
#include <hip/hip_bf16.h>

// MoE FFN: T=4096, H=I=1024, E=8, top-2. Inputs f32, output f32.
// Fast path (ws>=72.2MB, proven R6): prep(router+bucket+cvtX+zero-out) ->
// cvtW_all (bf16 [e][n][k]) -> GEMM1 (gate+up+SiLU, global_load_lds, XOR
// swizzle, XCD-pinned blocks) -> Hbuf(bf16) -> GEMM2 (down, fused weighted
// atomicAdd into out, XCD-pinned). Fallback: R5 2-pass f32-staging path.

#define T_TOK 4096
#define HDIM  1024
#define NEXP  8
#define RROWS (T_TOK * 2)
#define MAXPE T_TOK

typedef unsigned short u16;
typedef short v8s __attribute__((ext_vector_type(8)));
typedef float v4f __attribute__((ext_vector_type(4)));
typedef __attribute__((address_space(3))) unsigned int as3_u32;
typedef const __attribute__((address_space(1))) unsigned int as1_u32c;

__device__ __forceinline__ float b2f(u16 u) {
    union { unsigned int i; float f; } v; v.i = ((unsigned int)u) << 16; return v.f;
}
__device__ __forceinline__ u16 f2b(float f) {
    union { float f; unsigned int i; } v; v.f = f;
    unsigned int x = v.i;
    return (u16)((x + 0x7FFFu + ((x >> 16) & 1u)) >> 16);
}
__device__ __forceinline__ unsigned int pack2(float a, float b) {
    return (unsigned int)f2b(a) | ((unsigned int)f2b(b) << 16);
}
__device__ __forceinline__ void stage16(const u16* g, u16* l) {
    __builtin_amdgcn_global_load_lds((as1_u32c*)g, (as3_u32*)l, 16, 0, 0);
}

// ---------------- prep: cvtX + zero(out) + router + bucket ----------------
__global__ __launch_bounds__(256)
void prep_kernel(const float* __restrict__ X, const float* __restrict__ RL,
                 u16* __restrict__ Xb, float* __restrict__ outZ,
                 int* __restrict__ ids, float* __restrict__ wts,
                 int* __restrict__ counts, int* __restrict__ rowbuf) {
    int gid = blockIdx.x * 256 + threadIdx.x;       // 0 .. 1048575
    int i = gid * 4;
    float4 f = *(const float4*)(X + i);
    uint2 o; o.x = pack2(f.x, f.y); o.y = pack2(f.z, f.w);
    *(uint2*)(Xb + i) = o;
    float4 z = {0.f, 0.f, 0.f, 0.f};
    *(float4*)(outZ + i) = z;

    if (gid < T_TOK) {                               // router + bucket for token gid
        int t = gid;
        float4 a = *(const float4*)(RL + t * NEXP);
        float4 b = *(const float4*)(RL + t * NEXP + 4);
        float l[NEXP] = {a.x, a.y, a.z, a.w, b.x, b.y, b.z, b.w};
        int i0 = 0;
#pragma unroll
        for (int q = 1; q < NEXP; q++) if (l[q] > l[i0]) i0 = q;
        int i1 = (i0 == 0) ? 1 : 0;
#pragma unroll
        for (int q = 0; q < NEXP; q++) if (q != i0 && l[q] > l[i1]) i1 = q;
        float w0 = 1.0f / (1.0f + expf(l[i1] - l[i0]));
        ids[2 * t] = i0;     ids[2 * t + 1] = i1;
        wts[2 * t] = w0;     wts[2 * t + 1] = 1.0f - w0;
        int p0 = atomicAdd(&counts[i0], 1);
        rowbuf[i0 * MAXPE + p0] = 2 * t;
        int p1 = atomicAdd(&counts[i1], 1);
        rowbuf[i1 * MAXPE + p1] = 2 * t + 1;
    }
}

// ---------------- cvtW_all: WU and WD -> bf16 [e][n][k] in one launch ----------------
__global__ void cvtW_all(const float* __restrict__ WU, const float* __restrict__ WD,
                         u16* __restrict__ WtU, u16* __restrict__ WtD) {
    __shared__ __align__(16) u16 tile[64 * 72];
    int e = blockIdx.z;
    const float* Wb; u16* Wtb; int N;
    int bx = blockIdx.x;
    if (bx < 32) { Wb = WU + (size_t)e * 1024 * 2048; Wtb = WtU + (size_t)e * 2048 * 1024; N = 2048; }
    else         { Wb = WD + (size_t)e * 1024 * 1024; Wtb = WtD + (size_t)e * 1024 * 1024; N = 1024; bx -= 32; }
    int n0 = bx * 64, k0 = blockIdx.y * 64;
    int r = threadIdx.x >> 4, c4 = (threadIdx.x & 15) * 4;
#pragma unroll
    for (int j = 0; j < 4; j++) {
        int k = r + j * 16;
        float4 f = *(const float4*)(Wb + (size_t)(k0 + k) * N + n0 + c4);
        tile[(c4 + 0) * 72 + k] = f2b(f.x);
        tile[(c4 + 1) * 72 + k] = f2b(f.y);
        tile[(c4 + 2) * 72 + k] = f2b(f.z);
        tile[(c4 + 3) * 72 + k] = f2b(f.w);
    }
    __syncthreads();
    int n = threadIdx.x >> 2, kc = (threadIdx.x & 3) * 16;
    uint4 v0 = *(const uint4*)&tile[n * 72 + kc];
    uint4 v1 = *(const uint4*)&tile[n * 72 + kc + 8];
    u16* dst = Wtb + (size_t)(n0 + n) * 1024 + k0 + kc;
    *(uint4*)dst = v0;
    *(uint4*)(dst + 8) = v1;
}

// ---------------- grouped GEMM, global_load_lds + XOR swizzle + XCD pinning ----------------
// 1-D grid. xcd = i&7; blocks sharing one (e,ct) B-slab all map to one XCD so
// the slab stays in that XCD's L2 across rt-blocks.
// PHASE1: 4096 blocks; p=(k&15)*8+xcd -> e=p>>4, ct=p&15 (64 gate + 64 up cols).
// PHASE2: 2048 blocks; p=(k&7)*8+xcd  -> e=p>>3, ct=p&7  (128 cols), atomic out.
template<int PHASE>
__global__ __launch_bounds__(256)
void mfma_gemm(const u16* __restrict__ A, const u16* __restrict__ Bt,
               u16* __restrict__ H, float* __restrict__ OUT,
               const int* __restrict__ counts, const int* __restrict__ rowbuf,
               const float* __restrict__ wts) {
    const int bi = blockIdx.x;
    const int xcd = bi & 7, kb = bi >> 3;
    int e, ct, rt;
    if (PHASE == 1) { int p = (kb & 15) * 8 + xcd; e = p >> 4; ct = p & 15; rt = kb >> 4; }
    else            { int p = (kb & 7) * 8 + xcd;  e = p >> 3; ct = p & 7;  rt = kb >> 3; }
    const int cnt = counts[e];
    if (rt * 128 >= cnt) return;
    const int tid = threadIdx.x;
    const int lane = tid & 63, wave = tid >> 6;

    __shared__ __align__(16) u16 sA[128 * 64];   // [row][k], no pad (global_load_lds)
    __shared__ __align__(16) u16 sB[128 * 64];   // [n][k]
    __shared__ int srid[128];

    if (tid < 128) {
        int idx = rt * 128 + tid;
        srid[tid] = (idx < cnt) ? rowbuf[e * MAXPE + idx] : -1;
    }
    __syncthreads();

    // staging: region p covers 8 tile rows; lane l handles row l>>3, fetches
    // global chunk ((l&7)^(l>>3)) into LDS slot (l&7)  -> XOR bank swizzle.
    const int lrow = lane >> 3;
    const int lchunk = (lane & 7) ^ lrow;
    const u16* aPtr[4]; const u16* bPtr[4];
    u16 *aDst[4], *bDst[4];
#pragma unroll
    for (int p = 0; p < 4; p++) {
        int region = p * 4 + wave;
        int r = region * 8 + lrow;
        int rid = srid[r];
        int arow = (rid < 0) ? 0 : (PHASE == 1 ? (rid >> 1) : rid);
        aPtr[p] = A + (size_t)arow * 1024 + lchunk * 8;
        aDst[p] = sA + region * 512 + lane * 8;
        int n;
        if (PHASE == 1) n = (r < 64) ? (ct * 64 + r) : (1024 + ct * 64 + (r - 64));
        else            n = ct * 128 + r;
        bPtr[p] = Bt + (size_t)e * (PHASE == 1 ? 2048 : 1024) * 1024
                     + (size_t)n * 1024 + lchunk * 8;
        bDst[p] = sB + region * 512 + lane * 8;
    }

    const int quad = lane >> 4, mr = lane & 15;
    const int swA = mr & 7;
    const v4f zf = {0.f, 0.f, 0.f, 0.f};
    v4f acc[2][8];
#pragma unroll
    for (int i = 0; i < 2; i++)
#pragma unroll
        for (int j = 0; j < 8; j++) acc[i][j] = zf;

    for (int kk = 0; kk < 16; kk++) {            // BK=64
        __syncthreads();
#pragma unroll
        for (int p = 0; p < 4; p++) {
            stage16(aPtr[p] + kk * 64, aDst[p]);
            stage16(bPtr[p] + kk * 64, bDst[p]);
        }
        __syncthreads();
#pragma unroll
        for (int kh = 0; kh < 2; kh++) {
            const int c = kh * 4 + quad;
            v8s a0 = *(const v8s*)(sA + (wave * 32 + mr) * 64 + ((c ^ swA) * 8));
            v8s a1 = *(const v8s*)(sA + (wave * 32 + 16 + mr) * 64 + ((c ^ swA) * 8));
#pragma unroll
            for (int nf = 0; nf < 8; nf++) {
                v8s b = *(const v8s*)(sB + (nf * 16 + mr) * 64 + ((c ^ swA) * 8));
                acc[0][nf] = __builtin_amdgcn_mfma_f32_16x16x32_bf16(a0, b, acc[0][nf], 0, 0, 0);
                acc[1][nf] = __builtin_amdgcn_mfma_f32_16x16x32_bf16(a1, b, acc[1][nf], 0, 0, 0);
            }
        }
    }

    // C/D layout: col = lane&15, row = quad*4+reg
#pragma unroll
    for (int mf = 0; mf < 2; mf++) {
#pragma unroll
        for (int reg = 0; reg < 4; reg++) {
            int rl = wave * 32 + mf * 16 + quad * 4 + reg;
            int grow = srid[rl];
            if (grow < 0) continue;
            if (PHASE == 1) {
                size_t base = (size_t)grow * 1024 + ct * 64 + mr;
#pragma unroll
                for (int nf = 0; nf < 4; nf++) {
                    float g = acc[mf][nf][reg], u = acc[mf][nf + 4][reg];
                    H[base + nf * 16] = f2b((g / (1.0f + expf(-g))) * u);
                }
            } else {
                float w = wts[grow];
                size_t base = (size_t)(grow >> 1) * 1024 + ct * 128 + mr;
#pragma unroll
                for (int nf = 0; nf < 8; nf++)
                    atomicAdd(&OUT[base + nf * 16], w * acc[mf][nf][reg]);
            }
        }
    }
}

// ================= R5 fallback path =================
__global__ void router_kernel(const float* __restrict__ logits,
                              int* __restrict__ ids, float* __restrict__ wts) {
    int t = blockIdx.x * blockDim.x + threadIdx.x;
    if (t >= T_TOK) return;
    float4 a = *(const float4*)(logits + t * NEXP);
    float4 b = *(const float4*)(logits + t * NEXP + 4);
    float l[NEXP] = {a.x, a.y, a.z, a.w, b.x, b.y, b.z, b.w};
    int i0 = 0;
#pragma unroll
    for (int i = 1; i < NEXP; i++) if (l[i] > l[i0]) i0 = i;
    int i1 = (i0 == 0) ? 1 : 0;
#pragma unroll
    for (int i = 0; i < NEXP; i++) if (i != i0 && l[i] > l[i1]) i1 = i;
    float w0 = 1.0f / (1.0f + expf(l[i1] - l[i0]));
    ids[2 * t] = i0;     ids[2 * t + 1] = i1;
    wts[2 * t] = w0;     wts[2 * t + 1] = 1.0f - w0;
}

__global__ void bucket_kernel(const int* __restrict__ ids,
                              int* __restrict__ counts, int* __restrict__ rowbuf) {
    int r = blockIdx.x * blockDim.x + threadIdx.x;
    if (r >= RROWS) return;
    int e = ids[r];
    int pos = atomicAdd(&counts[e], 1);
    rowbuf[e * MAXPE + pos] = r;
}

template<int GATED, int AF32>
__global__ __launch_bounds__(256)
void moe_gemm_kernel(const void* __restrict__ Av,
                     const float* __restrict__ B,
                     u16* __restrict__ C,
                     const int* __restrict__ counts,
                     const int* __restrict__ rowbuf,
                     int rowShift, int NB) {
    const int e   = blockIdx.z;
    const int cnt = counts[e];
    const int rt  = blockIdx.y;
    if (rt * 128 >= cnt) return;
    const int ct  = blockIdx.x;
    const int tid = threadIdx.x;

    __shared__ __align__(16) u16 sA[128 * 40];
    __shared__ __align__(16) u16 sB[(GATED ? 2 : 1) * 64 * 40];
    __shared__ int srid[128];

    if (tid < 128) {
        int idx = rt * 128 + tid;
        srid[tid] = (idx < cnt) ? rowbuf[e * MAXPE + idx] : -1;
    }
    __syncthreads();

    const int ar = tid >> 1, ac = (tid & 1) * 16;
    int arid = srid[ar];
    const float* aSrcF = 0; const u16* aSrcH = 0;
    if (arid >= 0) {
        if (AF32) aSrcF = (const float*)Av + (size_t)(arid >> rowShift) * HDIM + ac;
        else      aSrcH = (const u16*)Av + (size_t)(arid >> rowShift) * HDIM + ac;
    }
    u16* aDst = sA + ar * 40 + ac;

    const int kq2 = (tid >> 4) * 2, n4 = (tid & 15) * 4;
    const float* bSrcG = B + (size_t)e * 1024 * NB + (size_t)kq2 * NB + ct * 64 + n4;
    const float* bSrcU = bSrcG + 1024;

    const int lane = tid & 63, wave = tid >> 6;
    const int quad = lane >> 4, mr = lane & 15;

    const v4f zf = {0.f, 0.f, 0.f, 0.f};
    v4f accG[2][4], accU[2][4];
#pragma unroll
    for (int i = 0; i < 2; i++)
#pragma unroll
        for (int j = 0; j < 4; j++) { accG[i][j] = zf; accU[i][j] = zf; }

    for (int kk = 0; kk < HDIM / 32; kk++) {
        uint4 aw0 = make_uint4(0, 0, 0, 0), aw1 = make_uint4(0, 0, 0, 0);
        if (AF32) {
            if (aSrcF) {
                float4 f0 = *(const float4*)(aSrcF + kk * 32);
                float4 f1 = *(const float4*)(aSrcF + kk * 32 + 4);
                float4 f2 = *(const float4*)(aSrcF + kk * 32 + 8);
                float4 f3 = *(const float4*)(aSrcF + kk * 32 + 12);
                aw0 = make_uint4(pack2(f0.x, f0.y), pack2(f0.z, f0.w),
                                 pack2(f1.x, f1.y), pack2(f1.z, f1.w));
                aw1 = make_uint4(pack2(f2.x, f2.y), pack2(f2.z, f2.w),
                                 pack2(f3.x, f3.y), pack2(f3.z, f3.w));
            }
        } else {
            if (aSrcH) {
                aw0 = *(const uint4*)(aSrcH + kk * 32);
                aw1 = *(const uint4*)(aSrcH + kk * 32 + 8);
            }
        }
        const size_t bOff = (size_t)kk * 32 * NB;
        float4 g0 = *(const float4*)(bSrcG + bOff);
        float4 g1 = *(const float4*)(bSrcG + bOff + NB);
        float4 u0 = make_float4(0, 0, 0, 0), u1 = make_float4(0, 0, 0, 0);
        if (GATED) {
            u0 = *(const float4*)(bSrcU + bOff);
            u1 = *(const float4*)(bSrcU + bOff + NB);
        }

        __syncthreads();
        *(uint4*)aDst = aw0;
        *(uint4*)(aDst + 8) = aw1;
        {
            const float gx[4] = {g0.x, g0.y, g0.z, g0.w};
            const float gy[4] = {g1.x, g1.y, g1.z, g1.w};
#pragma unroll
            for (int j = 0; j < 4; j++)
                *(unsigned int*)&sB[(n4 + j) * 40 + kq2] = pack2(gx[j], gy[j]);
            if (GATED) {
                const float ux[4] = {u0.x, u0.y, u0.z, u0.w};
                const float uy[4] = {u1.x, u1.y, u1.z, u1.w};
#pragma unroll
                for (int j = 0; j < 4; j++)
                    *(unsigned int*)&sB[64 * 40 + (n4 + j) * 40 + kq2] = pack2(ux[j], uy[j]);
            }
        }
        __syncthreads();

        v8s af0 = *(const v8s*)(sA + (wave * 32 + mr) * 40 + quad * 8);
        v8s af1 = *(const v8s*)(sA + (wave * 32 + 16 + mr) * 40 + quad * 8);
#pragma unroll
        for (int nf = 0; nf < 4; nf++) {
            v8s bg = *(const v8s*)(sB + (nf * 16 + mr) * 40 + quad * 8);
            accG[0][nf] = __builtin_amdgcn_mfma_f32_16x16x32_bf16(af0, bg, accG[0][nf], 0, 0, 0);
            accG[1][nf] = __builtin_amdgcn_mfma_f32_16x16x32_bf16(af1, bg, accG[1][nf], 0, 0, 0);
            if (GATED) {
                v8s bu = *(const v8s*)(sB + 64 * 40 + (nf * 16 + mr) * 40 + quad * 8);
                accU[0][nf] = __builtin_amdgcn_mfma_f32_16x16x32_bf16(af0, bu, accU[0][nf], 0, 0, 0);
                accU[1][nf] = __builtin_amdgcn_mfma_f32_16x16x32_bf16(af1, bu, accU[1][nf], 0, 0, 0);
            }
        }
    }

#pragma unroll
    for (int mf = 0; mf < 2; mf++) {
#pragma unroll
        for (int reg = 0; reg < 4; reg++) {
            int rl = wave * 32 + mf * 16 + quad * 4 + reg;
            int grow = srid[rl];
            if (grow < 0) continue;
            size_t base = (size_t)grow * 1024 + ct * 64 + mr;
#pragma unroll
            for (int nf = 0; nf < 4; nf++) {
                float g = accG[mf][nf][reg];
                float val;
                if (GATED) {
                    float u = accU[mf][nf][reg];
                    val = (g / (1.0f + expf(-g))) * u;
                } else {
                    val = g;
                }
                C[base + nf * 16] = f2b(val);
            }
        }
    }
}

__global__ void combine_kernel(const u16* __restrict__ accb,
                               const float* __restrict__ wts,
                               float* __restrict__ out) {
    int g = blockIdx.x * blockDim.x + threadIdx.x;
    int t = g >> 8;
    int c = (g & 255) * 4;
    float w0 = wts[2 * t], w1 = wts[2 * t + 1];
    ushort4 a = *(const ushort4*)(accb + (size_t)(2 * t) * 1024 + c);
    ushort4 b = *(const ushort4*)(accb + (size_t)(2 * t + 1) * 1024 + c);
    float4 o;
    o.x = w0 * b2f(a.x) + w1 * b2f(b.x);
    o.y = w0 * b2f(a.y) + w1 * b2f(b.y);
    o.z = w0 * b2f(a.z) + w1 * b2f(b.z);
    o.w = w0 * b2f(a.w) + w1 * b2f(b.w);
    *(float4*)(out + (size_t)t * 1024 + c) = o;
}

extern "C" void kernel_launch(void* const* d_in, const int* in_sizes, int n_in,
                              void* d_out, int out_size, void* d_ws, size_t ws_size,
                              hipStream_t stream) {
    const float *X = 0, *RL = 0, *WU = 0, *WD = 0;
    for (int i = 0; i < n_in; i++) {
        switch (in_sizes[i]) {
            case T_TOK * HDIM:        X  = (const float*)d_in[i]; break;
            case T_TOK * NEXP:        RL = (const float*)d_in[i]; break;
            case NEXP * HDIM * 2048:  WU = (const float*)d_in[i]; break;
            case NEXP * HDIM * 1024:  WD = (const float*)d_in[i]; break;
            default: break;
        }
    }
    if (!X)  X  = (const float*)d_in[0];
    if (!RL) RL = (const float*)d_in[1];
    if (!WU) WU = (const float*)d_in[2];
    if (!WD) WD = (const float*)d_in[3];
    float* OUT = (float*)d_out;

    char* ws = (char*)d_ws;
    int*   ids    = (int*)(ws + 0);
    float* wts    = (float*)(ws + 32768);
    int*   counts = (int*)(ws + 65536);
    int*   rowbuf = (int*)(ws + 65792);               // ends 196864
    u16* Xb   = (u16*)(ws + 196864);                  // 8 MB
    u16* WtU  = (u16*)(ws + 8585472);                 // 32 MB
    u16* WtD  = (u16*)(ws + 42139904);                // 16 MB
    u16* HbufF= (u16*)(ws + 58917120);                // 16 MB
    const size_t needFast = 75694336ull;
    u16* Hbuf = (u16*)(ws + 196864);
    u16* Acc  = (u16*)(ws + 196864 + 16777216);

    hipMemsetAsync(counts, 0, NEXP * sizeof(int), stream);

    if (ws_size >= needFast) {
        prep_kernel<<<T_TOK * HDIM / 1024, 256, 0, stream>>>(
            X, RL, Xb, OUT, ids, wts, counts, rowbuf);
        cvtW_all<<<dim3(48, 16, NEXP), 256, 0, stream>>>(WU, WD, WtU, WtD);
        mfma_gemm<1><<<4096, 256, 0, stream>>>(Xb, WtU, HbufF, OUT, counts, rowbuf, wts);
        mfma_gemm<2><<<2048, 256, 0, stream>>>(HbufF, WtD, HbufF, OUT, counts, rowbuf, wts);
    } else {
        router_kernel<<<T_TOK / 256, 256, 0, stream>>>(RL, ids, wts);
        bucket_kernel<<<RROWS / 256, 256, 0, stream>>>(ids, counts, rowbuf);
        moe_gemm_kernel<1, 1><<<dim3(16, 32, NEXP), 256, 0, stream>>>(
            (const void*)X, WU, Hbuf, counts, rowbuf, 1, 2048);
        moe_gemm_kernel<0, 0><<<dim3(16, 32, NEXP), 256, 0, stream>>>(
            (const void*)Hbuf, WD, Acc, counts, rowbuf, 0, 1024);
        combine_kernel<<<T_TOK, 256, 0, stream>>>(Acc, wts, OUT);
    }
}

// Round 8
// 273.533 us; speedup vs baseline: 1.3165x; 1.0442x over previous
//
#include <hip/hip_runtime.h>
#include <hip/hip_bf16.h>

// MoE FFN: T=4096, H=I=1024, E=8, top-2. Inputs f32, output f32.
// Fast path (ws>=72.2MB, proven): prep(router+bucket+cvtX) -> cvtW_all
// (bf16 [e][n][k]) -> GEMM1 (gate+up+SiLU, global_load_lds, XOR swizzle)
// -> Hbuf(bf16) -> GEMM2 (down) -> Acc(bf16, aliases dead WtU) -> combine(f32).
// No atomics anywhere in the hot path. Fallback: R5 2-pass f32-staging path.

#define T_TOK 4096
#define HDIM  1024
#define NEXP  8
#define RROWS (T_TOK * 2)
#define MAXPE T_TOK

typedef unsigned short u16;
typedef short v8s __attribute__((ext_vector_type(8)));
typedef float v4f __attribute__((ext_vector_type(4)));
typedef __attribute__((address_space(3))) unsigned int as3_u32;
typedef const __attribute__((address_space(1))) unsigned int as1_u32c;

__device__ __forceinline__ float b2f(u16 u) {
    union { unsigned int i; float f; } v; v.i = ((unsigned int)u) << 16; return v.f;
}
__device__ __forceinline__ u16 f2b(float f) {
    union { float f; unsigned int i; } v; v.f = f;
    unsigned int x = v.i;
    return (u16)((x + 0x7FFFu + ((x >> 16) & 1u)) >> 16);
}
__device__ __forceinline__ unsigned int pack2(float a, float b) {
    return (unsigned int)f2b(a) | ((unsigned int)f2b(b) << 16);
}
__device__ __forceinline__ void stage16(const u16* g, u16* l) {
    __builtin_amdgcn_global_load_lds((as1_u32c*)g, (as3_u32*)l, 16, 0, 0);
}

// ---------------- prep: cvtX + router + bucket ----------------
__global__ __launch_bounds__(256)
void prep_kernel(const float* __restrict__ X, const float* __restrict__ RL,
                 u16* __restrict__ Xb,
                 int* __restrict__ ids, float* __restrict__ wts,
                 int* __restrict__ counts, int* __restrict__ rowbuf) {
    int gid = blockIdx.x * 256 + threadIdx.x;       // 0 .. 1048575
    int i = gid * 4;
    float4 f = *(const float4*)(X + i);
    uint2 o; o.x = pack2(f.x, f.y); o.y = pack2(f.z, f.w);
    *(uint2*)(Xb + i) = o;

    if (gid < T_TOK) {
        int t = gid;
        float4 a = *(const float4*)(RL + t * NEXP);
        float4 b = *(const float4*)(RL + t * NEXP + 4);
        float l[NEXP] = {a.x, a.y, a.z, a.w, b.x, b.y, b.z, b.w};
        int i0 = 0;
#pragma unroll
        for (int q = 1; q < NEXP; q++) if (l[q] > l[i0]) i0 = q;
        int i1 = (i0 == 0) ? 1 : 0;
#pragma unroll
        for (int q = 0; q < NEXP; q++) if (q != i0 && l[q] > l[i1]) i1 = q;
        float w0 = 1.0f / (1.0f + expf(l[i1] - l[i0]));
        ids[2 * t] = i0;     ids[2 * t + 1] = i1;
        wts[2 * t] = w0;     wts[2 * t + 1] = 1.0f - w0;
        int p0 = atomicAdd(&counts[i0], 1);
        rowbuf[i0 * MAXPE + p0] = 2 * t;
        int p1 = atomicAdd(&counts[i1], 1);
        rowbuf[i1 * MAXPE + p1] = 2 * t + 1;
    }
}

// ---------------- cvtW_all: WU and WD -> bf16 [e][n][k] ----------------
__global__ void cvtW_all(const float* __restrict__ WU, const float* __restrict__ WD,
                         u16* __restrict__ WtU, u16* __restrict__ WtD) {
    __shared__ __align__(16) u16 tile[64 * 72];
    int e = blockIdx.z;
    const float* Wb; u16* Wtb; int N;
    int bx = blockIdx.x;
    if (bx < 32) { Wb = WU + (size_t)e * 1024 * 2048; Wtb = WtU + (size_t)e * 2048 * 1024; N = 2048; }
    else         { Wb = WD + (size_t)e * 1024 * 1024; Wtb = WtD + (size_t)e * 1024 * 1024; N = 1024; bx -= 32; }
    int n0 = bx * 64, k0 = blockIdx.y * 64;
    int r = threadIdx.x >> 4, c4 = (threadIdx.x & 15) * 4;
#pragma unroll
    for (int j = 0; j < 4; j++) {
        int k = r + j * 16;
        float4 f = *(const float4*)(Wb + (size_t)(k0 + k) * N + n0 + c4);
        tile[(c4 + 0) * 72 + k] = f2b(f.x);
        tile[(c4 + 1) * 72 + k] = f2b(f.y);
        tile[(c4 + 2) * 72 + k] = f2b(f.z);
        tile[(c4 + 3) * 72 + k] = f2b(f.w);
    }
    __syncthreads();
    int n = threadIdx.x >> 2, kc = (threadIdx.x & 3) * 16;
    uint4 v0 = *(const uint4*)&tile[n * 72 + kc];
    uint4 v1 = *(const uint4*)&tile[n * 72 + kc + 8];
    u16* dst = Wtb + (size_t)(n0 + n) * 1024 + k0 + kc;
    *(uint4*)dst = v0;
    *(uint4*)(dst + 8) = v1;
}

// ---------------- grouped GEMM, global_load_lds + XOR swizzle ----------------
// PHASE1: 4096 blocks; A=Xb (row=grow>>1), B=WtU; dual 64-col gate/up tile;
//         epilogue silu*u -> H (bf16).
// PHASE2: 2048 blocks; A=Hbuf (row=grow), B=WtD; 128-col tile;
//         epilogue plain bf16 store -> H (=Acc). NO atomics.
template<int PHASE>
__global__ __launch_bounds__(256)
void mfma_gemm(const u16* __restrict__ A, const u16* __restrict__ Bt,
               u16* __restrict__ H,
               const int* __restrict__ counts, const int* __restrict__ rowbuf) {
    const int bi = blockIdx.x;
    const int xcd = bi & 7, kb = bi >> 3;
    int e, ct, rt;
    if (PHASE == 1) { int p = (kb & 15) * 8 + xcd; e = p >> 4; ct = p & 15; rt = kb >> 4; }
    else            { int p = (kb & 7) * 8 + xcd;  e = p >> 3; ct = p & 7;  rt = kb >> 3; }
    const int cnt = counts[e];
    if (rt * 128 >= cnt) return;
    const int tid = threadIdx.x;
    const int lane = tid & 63, wave = tid >> 6;

    __shared__ __align__(16) u16 sA[128 * 64];   // [row][k], no pad (global_load_lds)
    __shared__ __align__(16) u16 sB[128 * 64];   // [n][k]
    __shared__ int srid[128];

    if (tid < 128) {
        int idx = rt * 128 + tid;
        srid[tid] = (idx < cnt) ? rowbuf[e * MAXPE + idx] : -1;
    }
    __syncthreads();

    const int lrow = lane >> 3;
    const int lchunk = (lane & 7) ^ lrow;        // XOR bank swizzle on gather side
    const u16* aPtr[4]; const u16* bPtr[4];
    u16 *aDst[4], *bDst[4];
#pragma unroll
    for (int p = 0; p < 4; p++) {
        int region = p * 4 + wave;
        int r = region * 8 + lrow;
        int rid = srid[r];
        int arow = (rid < 0) ? 0 : (PHASE == 1 ? (rid >> 1) : rid);
        aPtr[p] = A + (size_t)arow * 1024 + lchunk * 8;
        aDst[p] = sA + region * 512 + lane * 8;
        int n;
        if (PHASE == 1) n = (r < 64) ? (ct * 64 + r) : (1024 + ct * 64 + (r - 64));
        else            n = ct * 128 + r;
        bPtr[p] = Bt + (size_t)e * (PHASE == 1 ? 2048 : 1024) * 1024
                     + (size_t)n * 1024 + lchunk * 8;
        bDst[p] = sB + region * 512 + lane * 8;
    }

    const int quad = lane >> 4, mr = lane & 15;
    const int swA = mr & 7;
    const v4f zf = {0.f, 0.f, 0.f, 0.f};
    v4f acc[2][8];
#pragma unroll
    for (int i = 0; i < 2; i++)
#pragma unroll
        for (int j = 0; j < 8; j++) acc[i][j] = zf;

    for (int kk = 0; kk < 16; kk++) {            // BK=64
        __syncthreads();
#pragma unroll
        for (int p = 0; p < 4; p++) {
            stage16(aPtr[p] + kk * 64, aDst[p]);
            stage16(bPtr[p] + kk * 64, bDst[p]);
        }
        __syncthreads();
#pragma unroll
        for (int kh = 0; kh < 2; kh++) {
            const int c = kh * 4 + quad;
            v8s a0 = *(const v8s*)(sA + (wave * 32 + mr) * 64 + ((c ^ swA) * 8));
            v8s a1 = *(const v8s*)(sA + (wave * 32 + 16 + mr) * 64 + ((c ^ swA) * 8));
#pragma unroll
            for (int nf = 0; nf < 8; nf++) {
                v8s b = *(const v8s*)(sB + (nf * 16 + mr) * 64 + ((c ^ swA) * 8));
                acc[0][nf] = __builtin_amdgcn_mfma_f32_16x16x32_bf16(a0, b, acc[0][nf], 0, 0, 0);
                acc[1][nf] = __builtin_amdgcn_mfma_f32_16x16x32_bf16(a1, b, acc[1][nf], 0, 0, 0);
            }
        }
    }

    // C/D layout: col = lane&15, row = quad*4+reg
#pragma unroll
    for (int mf = 0; mf < 2; mf++) {
#pragma unroll
        for (int reg = 0; reg < 4; reg++) {
            int rl = wave * 32 + mf * 16 + quad * 4 + reg;
            int grow = srid[rl];
            if (grow < 0) continue;
            if (PHASE == 1) {
                size_t base = (size_t)grow * 1024 + ct * 64 + mr;
#pragma unroll
                for (int nf = 0; nf < 4; nf++) {
                    float g = acc[mf][nf][reg], u = acc[mf][nf + 4][reg];
                    H[base + nf * 16] = f2b((g / (1.0f + expf(-g))) * u);
                }
            } else {
                size_t base = (size_t)grow * 1024 + ct * 128 + mr;
#pragma unroll
                for (int nf = 0; nf < 8; nf++)
                    H[base + nf * 16] = f2b(acc[mf][nf][reg]);
            }
        }
    }
}

// ---------------- combine: out(f32)[t] = w0*acc[2t] + w1*acc[2t+1] ----------------
__global__ void combine_kernel(const u16* __restrict__ accb,
                               const float* __restrict__ wts,
                               float* __restrict__ out) {
    int g = blockIdx.x * blockDim.x + threadIdx.x;
    int t = g >> 8;
    int c = (g & 255) * 4;
    float w0 = wts[2 * t], w1 = wts[2 * t + 1];
    ushort4 a = *(const ushort4*)(accb + (size_t)(2 * t) * 1024 + c);
    ushort4 b = *(const ushort4*)(accb + (size_t)(2 * t + 1) * 1024 + c);
    float4 o;
    o.x = w0 * b2f(a.x) + w1 * b2f(b.x);
    o.y = w0 * b2f(a.y) + w1 * b2f(b.y);
    o.z = w0 * b2f(a.z) + w1 * b2f(b.z);
    o.w = w0 * b2f(a.w) + w1 * b2f(b.w);
    *(float4*)(out + (size_t)t * 1024 + c) = o;
}

// ================= R5 fallback path =================
__global__ void router_kernel(const float* __restrict__ logits,
                              int* __restrict__ ids, float* __restrict__ wts) {
    int t = blockIdx.x * blockDim.x + threadIdx.x;
    if (t >= T_TOK) return;
    float4 a = *(const float4*)(logits + t * NEXP);
    float4 b = *(const float4*)(logits + t * NEXP + 4);
    float l[NEXP] = {a.x, a.y, a.z, a.w, b.x, b.y, b.z, b.w};
    int i0 = 0;
#pragma unroll
    for (int i = 1; i < NEXP; i++) if (l[i] > l[i0]) i0 = i;
    int i1 = (i0 == 0) ? 1 : 0;
#pragma unroll
    for (int i = 0; i < NEXP; i++) if (i != i0 && l[i] > l[i1]) i1 = i;
    float w0 = 1.0f / (1.0f + expf(l[i1] - l[i0]));
    ids[2 * t] = i0;     ids[2 * t + 1] = i1;
    wts[2 * t] = w0;     wts[2 * t + 1] = 1.0f - w0;
}

__global__ void bucket_kernel(const int* __restrict__ ids,
                              int* __restrict__ counts, int* __restrict__ rowbuf) {
    int r = blockIdx.x * blockDim.x + threadIdx.x;
    if (r >= RROWS) return;
    int e = ids[r];
    int pos = atomicAdd(&counts[e], 1);
    rowbuf[e * MAXPE + pos] = r;
}

template<int GATED, int AF32>
__global__ __launch_bounds__(256)
void moe_gemm_kernel(const void* __restrict__ Av,
                     const float* __restrict__ B,
                     u16* __restrict__ C,
                     const int* __restrict__ counts,
                     const int* __restrict__ rowbuf,
                     int rowShift, int NB) {
    const int e   = blockIdx.z;
    const int cnt = counts[e];
    const int rt  = blockIdx.y;
    if (rt * 128 >= cnt) return;
    const int ct  = blockIdx.x;
    const int tid = threadIdx.x;

    __shared__ __align__(16) u16 sA[128 * 40];
    __shared__ __align__(16) u16 sB[(GATED ? 2 : 1) * 64 * 40];
    __shared__ int srid[128];

    if (tid < 128) {
        int idx = rt * 128 + tid;
        srid[tid] = (idx < cnt) ? rowbuf[e * MAXPE + idx] : -1;
    }
    __syncthreads();

    const int ar = tid >> 1, ac = (tid & 1) * 16;
    int arid = srid[ar];
    const float* aSrcF = 0; const u16* aSrcH = 0;
    if (arid >= 0) {
        if (AF32) aSrcF = (const float*)Av + (size_t)(arid >> rowShift) * HDIM + ac;
        else      aSrcH = (const u16*)Av + (size_t)(arid >> rowShift) * HDIM + ac;
    }
    u16* aDst = sA + ar * 40 + ac;

    const int kq2 = (tid >> 4) * 2, n4 = (tid & 15) * 4;
    const float* bSrcG = B + (size_t)e * 1024 * NB + (size_t)kq2 * NB + ct * 64 + n4;
    const float* bSrcU = bSrcG + 1024;

    const int lane = tid & 63, wave = tid >> 6;
    const int quad = lane >> 4, mr = lane & 15;

    const v4f zf = {0.f, 0.f, 0.f, 0.f};
    v4f accG[2][4], accU[2][4];
#pragma unroll
    for (int i = 0; i < 2; i++)
#pragma unroll
        for (int j = 0; j < 4; j++) { accG[i][j] = zf; accU[i][j] = zf; }

    for (int kk = 0; kk < HDIM / 32; kk++) {
        uint4 aw0 = make_uint4(0, 0, 0, 0), aw1 = make_uint4(0, 0, 0, 0);
        if (AF32) {
            if (aSrcF) {
                float4 f0 = *(const float4*)(aSrcF + kk * 32);
                float4 f1 = *(const float4*)(aSrcF + kk * 32 + 4);
                float4 f2 = *(const float4*)(aSrcF + kk * 32 + 8);
                float4 f3 = *(const float4*)(aSrcF + kk * 32 + 12);
                aw0 = make_uint4(pack2(f0.x, f0.y), pack2(f0.z, f0.w),
                                 pack2(f1.x, f1.y), pack2(f1.z, f1.w));
                aw1 = make_uint4(pack2(f2.x, f2.y), pack2(f2.z, f2.w),
                                 pack2(f3.x, f3.y), pack2(f3.z, f3.w));
            }
        } else {
            if (aSrcH) {
                aw0 = *(const uint4*)(aSrcH + kk * 32);
                aw1 = *(const uint4*)(aSrcH + kk * 32 + 8);
            }
        }
        const size_t bOff = (size_t)kk * 32 * NB;
        float4 g0 = *(const float4*)(bSrcG + bOff);
        float4 g1 = *(const float4*)(bSrcG + bOff + NB);
        float4 u0 = make_float4(0, 0, 0, 0), u1 = make_float4(0, 0, 0, 0);
        if (GATED) {
            u0 = *(const float4*)(bSrcU + bOff);
            u1 = *(const float4*)(bSrcU + bOff + NB);
        }

        __syncthreads();
        *(uint4*)aDst = aw0;
        *(uint4*)(aDst + 8) = aw1;
        {
            const float gx[4] = {g0.x, g0.y, g0.z, g0.w};
            const float gy[4] = {g1.x, g1.y, g1.z, g1.w};
#pragma unroll
            for (int j = 0; j < 4; j++)
                *(unsigned int*)&sB[(n4 + j) * 40 + kq2] = pack2(gx[j], gy[j]);
            if (GATED) {
                const float ux[4] = {u0.x, u0.y, u0.z, u0.w};
                const float uy[4] = {u1.x, u1.y, u1.z, u1.w};
#pragma unroll
                for (int j = 0; j < 4; j++)
                    *(unsigned int*)&sB[64 * 40 + (n4 + j) * 40 + kq2] = pack2(ux[j], uy[j]);
            }
        }
        __syncthreads();

        v8s af0 = *(const v8s*)(sA + (wave * 32 + mr) * 40 + quad * 8);
        v8s af1 = *(const v8s*)(sA + (wave * 32 + 16 + mr) * 40 + quad * 8);
#pragma unroll
        for (int nf = 0; nf < 4; nf++) {
            v8s bg = *(const v8s*)(sB + (nf * 16 + mr) * 40 + quad * 8);
            accG[0][nf] = __builtin_amdgcn_mfma_f32_16x16x32_bf16(af0, bg, accG[0][nf], 0, 0, 0);
            accG[1][nf] = __builtin_amdgcn_mfma_f32_16x16x32_bf16(af1, bg, accG[1][nf], 0, 0, 0);
            if (GATED) {
                v8s bu = *(const v8s*)(sB + 64 * 40 + (nf * 16 + mr) * 40 + quad * 8);
                accU[0][nf] = __builtin_amdgcn_mfma_f32_16x16x32_bf16(af0, bu, accU[0][nf], 0, 0, 0);
                accU[1][nf] = __builtin_amdgcn_mfma_f32_16x16x32_bf16(af1, bu, accU[1][nf], 0, 0, 0);
            }
        }
    }

#pragma unroll
    for (int mf = 0; mf < 2; mf++) {
#pragma unroll
        for (int reg = 0; reg < 4; reg++) {
            int rl = wave * 32 + mf * 16 + quad * 4 + reg;
            int grow = srid[rl];
            if (grow < 0) continue;
            size_t base = (size_t)grow * 1024 + ct * 64 + mr;
#pragma unroll
            for (int nf = 0; nf < 4; nf++) {
                float g = accG[mf][nf][reg];
                float val;
                if (GATED) {
                    float u = accU[mf][nf][reg];
                    val = (g / (1.0f + expf(-g))) * u;
                } else {
                    val = g;
                }
                C[base + nf * 16] = f2b(val);
            }
        }
    }
}

extern "C" void kernel_launch(void* const* d_in, const int* in_sizes, int n_in,
                              void* d_out, int out_size, void* d_ws, size_t ws_size,
                              hipStream_t stream) {
    const float *X = 0, *RL = 0, *WU = 0, *WD = 0;
    for (int i = 0; i < n_in; i++) {
        switch (in_sizes[i]) {
            case T_TOK * HDIM:        X  = (const float*)d_in[i]; break;
            case T_TOK * NEXP:        RL = (const float*)d_in[i]; break;
            case NEXP * HDIM * 2048:  WU = (const float*)d_in[i]; break;
            case NEXP * HDIM * 1024:  WD = (const float*)d_in[i]; break;
            default: break;
        }
    }
    if (!X)  X  = (const float*)d_in[0];
    if (!RL) RL = (const float*)d_in[1];
    if (!WU) WU = (const float*)d_in[2];
    if (!WD) WD = (const float*)d_in[3];
    float* OUT = (float*)d_out;

    char* ws = (char*)d_ws;
    int*   ids    = (int*)(ws + 0);
    float* wts    = (float*)(ws + 32768);
    int*   counts = (int*)(ws + 65536);
    int*   rowbuf = (int*)(ws + 65792);               // ends 196864
    u16* Xb   = (u16*)(ws + 196864);                  // 8 MB
    u16* WtU  = (u16*)(ws + 8585472);                 // 32 MB (dead after GEMM1)
    u16* WtD  = (u16*)(ws + 42139904);                // 16 MB
    u16* HbufF= (u16*)(ws + 58917120);                // 16 MB
    u16* AccF = WtU;                                  // 16 MB, aliases dead WtU
    const size_t needFast = 75694336ull;
    u16* Hbuf = (u16*)(ws + 196864);
    u16* Acc  = (u16*)(ws + 196864 + 16777216);

    hipMemsetAsync(counts, 0, NEXP * sizeof(int), stream);

    if (ws_size >= needFast) {
        prep_kernel<<<T_TOK * HDIM / 1024, 256, 0, stream>>>(
            X, RL, Xb, ids, wts, counts, rowbuf);
        cvtW_all<<<dim3(48, 16, NEXP), 256, 0, stream>>>(WU, WD, WtU, WtD);
        mfma_gemm<1><<<4096, 256, 0, stream>>>(Xb, WtU, HbufF, counts, rowbuf);
        mfma_gemm<2><<<2048, 256, 0, stream>>>(HbufF, WtD, AccF, counts, rowbuf);
        combine_kernel<<<T_TOK, 256, 0, stream>>>(AccF, wts, OUT);
    } else {
        router_kernel<<<T_TOK / 256, 256, 0, stream>>>(RL, ids, wts);
        bucket_kernel<<<RROWS / 256, 256, 0, stream>>>(ids, counts, rowbuf);
        moe_gemm_kernel<1, 1><<<dim3(16, 32, NEXP), 256, 0, stream>>>(
            (const void*)X, WU, Hbuf, counts, rowbuf, 1, 2048);
        moe_gemm_kernel<0, 0><<<dim3(16, 32, NEXP), 256, 0, stream>>>(
            (const void*)Hbuf, WD, Acc, counts, rowbuf, 0, 1024);
        combine_kernel<<<T_TOK, 256, 0, stream>>>(Acc, wts, OUT);
    }
}

// Round 9
// 264.405 us; speedup vs baseline: 1.3619x; 1.0345x over previous
//
#include <hip/hip_runtime.h>
#include <hip/hip_bf16.h>

// MoE FFN: T=4096, H=I=1024, E=8, top-2. Inputs f32, output f32.
// Fast path (ws>=72.2MB, proven): memset(counts) -> prep_all(cvtW + cvtX +
// router/bucket, one kernel) -> GEMM1 (gate+up+SiLU, global_load_lds, XOR
// swizzle) -> Hbuf(bf16) -> GEMM2 (down) -> Acc(bf16, aliases dead WtU) ->
// combine(f32). Fallback: R5 2-pass f32-staging path.

#define T_TOK 4096
#define HDIM  1024
#define NEXP  8
#define RROWS (T_TOK * 2)
#define MAXPE T_TOK

typedef unsigned short u16;
typedef short v8s __attribute__((ext_vector_type(8)));
typedef float v4f __attribute__((ext_vector_type(4)));
typedef __attribute__((address_space(3))) unsigned int as3_u32;
typedef const __attribute__((address_space(1))) unsigned int as1_u32c;

__device__ __forceinline__ float b2f(u16 u) {
    union { unsigned int i; float f; } v; v.i = ((unsigned int)u) << 16; return v.f;
}
__device__ __forceinline__ u16 f2b(float f) {
    union { float f; unsigned int i; } v; v.f = f;
    unsigned int x = v.i;
    return (u16)((x + 0x7FFFu + ((x >> 16) & 1u)) >> 16);
}
__device__ __forceinline__ unsigned int pack2(float a, float b) {
    return (unsigned int)f2b(a) | ((unsigned int)f2b(b) << 16);
}
__device__ __forceinline__ void stage16(const u16* g, u16* l) {
    __builtin_amdgcn_global_load_lds((as1_u32c*)g, (as3_u32*)l, 16, 0, 0);
}

// ---------------- prep_all: cvtW (blocks 0..6143) + cvtX (6144..10239)
//                  + router/bucket (10240..10255), one launch ----------------
__global__ __launch_bounds__(256)
void prep_all(const float* __restrict__ X, const float* __restrict__ RL,
              const float* __restrict__ WU, const float* __restrict__ WD,
              u16* __restrict__ Xb, u16* __restrict__ WtU, u16* __restrict__ WtD,
              int* __restrict__ ids, float* __restrict__ wts,
              int* __restrict__ counts, int* __restrict__ rowbuf) {
    __shared__ __align__(16) u16 tile[64 * 72];
    const int bx = blockIdx.x;
    const int tid = threadIdx.x;

    if (bx < 6144) {
        // ---- cvtW: W[e][1024k][N] f32 -> Wt[e][N][1024k] bf16 ----
        int e = bx / 768;
        int r2 = bx - e * 768;
        int ky = r2 / 48;
        int bxx = r2 - ky * 48;
        const float* Wb; u16* Wtb; int N;
        if (bxx < 32) { Wb = WU + (size_t)e * 1024 * 2048; Wtb = WtU + (size_t)e * 2048 * 1024; N = 2048; }
        else          { Wb = WD + (size_t)e * 1024 * 1024; Wtb = WtD + (size_t)e * 1024 * 1024; N = 1024; bxx -= 32; }
        int n0 = bxx * 64, k0 = ky * 64;
        int r = tid >> 4, c4 = (tid & 15) * 4;
#pragma unroll
        for (int j = 0; j < 4; j++) {
            int k = r + j * 16;
            float4 f = *(const float4*)(Wb + (size_t)(k0 + k) * N + n0 + c4);
            tile[(c4 + 0) * 72 + k] = f2b(f.x);
            tile[(c4 + 1) * 72 + k] = f2b(f.y);
            tile[(c4 + 2) * 72 + k] = f2b(f.z);
            tile[(c4 + 3) * 72 + k] = f2b(f.w);
        }
        __syncthreads();
        int n = tid >> 2, kc = (tid & 3) * 16;
        uint4 v0 = *(const uint4*)&tile[n * 72 + kc];
        uint4 v1 = *(const uint4*)&tile[n * 72 + kc + 8];
        u16* dst = Wtb + (size_t)(n0 + n) * 1024 + k0 + kc;
        *(uint4*)dst = v0;
        *(uint4*)(dst + 8) = v1;
    } else if (bx < 10240) {
        // ---- cvtX: f32 -> bf16 ----
        int i = ((bx - 6144) * 256 + tid) * 4;
        float4 f = *(const float4*)(X + i);
        uint2 o; o.x = pack2(f.x, f.y); o.y = pack2(f.z, f.w);
        *(uint2*)(Xb + i) = o;
    } else {
        // ---- router + bucket ----
        int t = (bx - 10240) * 256 + tid;
        float4 a = *(const float4*)(RL + t * NEXP);
        float4 b = *(const float4*)(RL + t * NEXP + 4);
        float l[NEXP] = {a.x, a.y, a.z, a.w, b.x, b.y, b.z, b.w};
        int i0 = 0;
#pragma unroll
        for (int q = 1; q < NEXP; q++) if (l[q] > l[i0]) i0 = q;
        int i1 = (i0 == 0) ? 1 : 0;
#pragma unroll
        for (int q = 0; q < NEXP; q++) if (q != i0 && l[q] > l[i1]) i1 = q;
        float w0 = 1.0f / (1.0f + expf(l[i1] - l[i0]));
        ids[2 * t] = i0;     ids[2 * t + 1] = i1;
        wts[2 * t] = w0;     wts[2 * t + 1] = 1.0f - w0;
        int p0 = atomicAdd(&counts[i0], 1);
        rowbuf[i0 * MAXPE + p0] = 2 * t;
        int p1 = atomicAdd(&counts[i1], 1);
        rowbuf[i1 * MAXPE + p1] = 2 * t + 1;
    }
}

// ---------------- grouped GEMM, global_load_lds + XOR swizzle ----------------
// PHASE1: 4096 blocks; A=Xb (row=grow>>1), B=WtU; dual 64-col gate/up tile;
//         epilogue silu*u -> H (bf16).
// PHASE2: 2048 blocks; A=Hbuf (row=grow), B=WtD; 128-col tile; bf16 store.
template<int PHASE>
__global__ __launch_bounds__(256)
void mfma_gemm(const u16* __restrict__ A, const u16* __restrict__ Bt,
               u16* __restrict__ H,
               const int* __restrict__ counts, const int* __restrict__ rowbuf) {
    const int bi = blockIdx.x;
    const int xcd = bi & 7, kb = bi >> 3;
    int e, ct, rt;
    if (PHASE == 1) { int p = (kb & 15) * 8 + xcd; e = p >> 4; ct = p & 15; rt = kb >> 4; }
    else            { int p = (kb & 7) * 8 + xcd;  e = p >> 3; ct = p & 7;  rt = kb >> 3; }
    const int cnt = counts[e];
    if (rt * 128 >= cnt) return;
    const int tid = threadIdx.x;
    const int lane = tid & 63, wave = tid >> 6;

    __shared__ __align__(16) u16 sA[128 * 64];   // [row][k], no pad (global_load_lds)
    __shared__ __align__(16) u16 sB[128 * 64];   // [n][k]
    __shared__ int srid[128];

    if (tid < 128) {
        int idx = rt * 128 + tid;
        srid[tid] = (idx < cnt) ? rowbuf[e * MAXPE + idx] : -1;
    }
    __syncthreads();

    const int lrow = lane >> 3;
    const int lchunk = (lane & 7) ^ lrow;        // XOR bank swizzle on gather side
    const u16* aPtr[4]; const u16* bPtr[4];
    u16 *aDst[4], *bDst[4];
#pragma unroll
    for (int p = 0; p < 4; p++) {
        int region = p * 4 + wave;
        int r = region * 8 + lrow;
        int rid = srid[r];
        int arow = (rid < 0) ? 0 : (PHASE == 1 ? (rid >> 1) : rid);
        aPtr[p] = A + (size_t)arow * 1024 + lchunk * 8;
        aDst[p] = sA + region * 512 + lane * 8;
        int n;
        if (PHASE == 1) n = (r < 64) ? (ct * 64 + r) : (1024 + ct * 64 + (r - 64));
        else            n = ct * 128 + r;
        bPtr[p] = Bt + (size_t)e * (PHASE == 1 ? 2048 : 1024) * 1024
                     + (size_t)n * 1024 + lchunk * 8;
        bDst[p] = sB + region * 512 + lane * 8;
    }

    const int quad = lane >> 4, mr = lane & 15;
    const int swA = mr & 7;
    const v4f zf = {0.f, 0.f, 0.f, 0.f};
    v4f acc[2][8];
#pragma unroll
    for (int i = 0; i < 2; i++)
#pragma unroll
        for (int j = 0; j < 8; j++) acc[i][j] = zf;

    for (int kk = 0; kk < 16; kk++) {            // BK=64
        __syncthreads();
#pragma unroll
        for (int p = 0; p < 4; p++) {
            stage16(aPtr[p] + kk * 64, aDst[p]);
            stage16(bPtr[p] + kk * 64, bDst[p]);
        }
        __syncthreads();
#pragma unroll
        for (int kh = 0; kh < 2; kh++) {
            const int c = kh * 4 + quad;
            v8s a0 = *(const v8s*)(sA + (wave * 32 + mr) * 64 + ((c ^ swA) * 8));
            v8s a1 = *(const v8s*)(sA + (wave * 32 + 16 + mr) * 64 + ((c ^ swA) * 8));
#pragma unroll
            for (int nf = 0; nf < 8; nf++) {
                v8s b = *(const v8s*)(sB + (nf * 16 + mr) * 64 + ((c ^ swA) * 8));
                acc[0][nf] = __builtin_amdgcn_mfma_f32_16x16x32_bf16(a0, b, acc[0][nf], 0, 0, 0);
                acc[1][nf] = __builtin_amdgcn_mfma_f32_16x16x32_bf16(a1, b, acc[1][nf], 0, 0, 0);
            }
        }
    }

    // C/D layout: col = lane&15, row = quad*4+reg
#pragma unroll
    for (int mf = 0; mf < 2; mf++) {
#pragma unroll
        for (int reg = 0; reg < 4; reg++) {
            int rl = wave * 32 + mf * 16 + quad * 4 + reg;
            int grow = srid[rl];
            if (grow < 0) continue;
            if (PHASE == 1) {
                size_t base = (size_t)grow * 1024 + ct * 64 + mr;
#pragma unroll
                for (int nf = 0; nf < 4; nf++) {
                    float g = acc[mf][nf][reg], u = acc[mf][nf + 4][reg];
                    H[base + nf * 16] = f2b((g / (1.0f + expf(-g))) * u);
                }
            } else {
                size_t base = (size_t)grow * 1024 + ct * 128 + mr;
#pragma unroll
                for (int nf = 0; nf < 8; nf++)
                    H[base + nf * 16] = f2b(acc[mf][nf][reg]);
            }
        }
    }
}

// ---------------- combine: out(f32)[t] = w0*acc[2t] + w1*acc[2t+1] ----------------
__global__ void combine_kernel(const u16* __restrict__ accb,
                               const float* __restrict__ wts,
                               float* __restrict__ out) {
    int g = blockIdx.x * blockDim.x + threadIdx.x;
    int t = g >> 8;
    int c = (g & 255) * 4;
    float w0 = wts[2 * t], w1 = wts[2 * t + 1];
    ushort4 a = *(const ushort4*)(accb + (size_t)(2 * t) * 1024 + c);
    ushort4 b = *(const ushort4*)(accb + (size_t)(2 * t + 1) * 1024 + c);
    float4 o;
    o.x = w0 * b2f(a.x) + w1 * b2f(b.x);
    o.y = w0 * b2f(a.y) + w1 * b2f(b.y);
    o.z = w0 * b2f(a.z) + w1 * b2f(b.z);
    o.w = w0 * b2f(a.w) + w1 * b2f(b.w);
    *(float4*)(out + (size_t)t * 1024 + c) = o;
}

// ================= R5 fallback path =================
__global__ void router_kernel(const float* __restrict__ logits,
                              int* __restrict__ ids, float* __restrict__ wts) {
    int t = blockIdx.x * blockDim.x + threadIdx.x;
    if (t >= T_TOK) return;
    float4 a = *(const float4*)(logits + t * NEXP);
    float4 b = *(const float4*)(logits + t * NEXP + 4);
    float l[NEXP] = {a.x, a.y, a.z, a.w, b.x, b.y, b.z, b.w};
    int i0 = 0;
#pragma unroll
    for (int i = 1; i < NEXP; i++) if (l[i] > l[i0]) i0 = i;
    int i1 = (i0 == 0) ? 1 : 0;
#pragma unroll
    for (int i = 0; i < NEXP; i++) if (i != i0 && l[i] > l[i1]) i1 = i;
    float w0 = 1.0f / (1.0f + expf(l[i1] - l[i0]));
    ids[2 * t] = i0;     ids[2 * t + 1] = i1;
    wts[2 * t] = w0;     wts[2 * t + 1] = 1.0f - w0;
}

__global__ void bucket_kernel(const int* __restrict__ ids,
                              int* __restrict__ counts, int* __restrict__ rowbuf) {
    int r = blockIdx.x * blockDim.x + threadIdx.x;
    if (r >= RROWS) return;
    int e = ids[r];
    int pos = atomicAdd(&counts[e], 1);
    rowbuf[e * MAXPE + pos] = r;
}

template<int GATED, int AF32>
__global__ __launch_bounds__(256)
void moe_gemm_kernel(const void* __restrict__ Av,
                     const float* __restrict__ B,
                     u16* __restrict__ C,
                     const int* __restrict__ counts,
                     const int* __restrict__ rowbuf,
                     int rowShift, int NB) {
    const int e   = blockIdx.z;
    const int cnt = counts[e];
    const int rt  = blockIdx.y;
    if (rt * 128 >= cnt) return;
    const int ct  = blockIdx.x;
    const int tid = threadIdx.x;

    __shared__ __align__(16) u16 sA[128 * 40];
    __shared__ __align__(16) u16 sB[(GATED ? 2 : 1) * 64 * 40];
    __shared__ int srid[128];

    if (tid < 128) {
        int idx = rt * 128 + tid;
        srid[tid] = (idx < cnt) ? rowbuf[e * MAXPE + idx] : -1;
    }
    __syncthreads();

    const int ar = tid >> 1, ac = (tid & 1) * 16;
    int arid = srid[ar];
    const float* aSrcF = 0; const u16* aSrcH = 0;
    if (arid >= 0) {
        if (AF32) aSrcF = (const float*)Av + (size_t)(arid >> rowShift) * HDIM + ac;
        else      aSrcH = (const u16*)Av + (size_t)(arid >> rowShift) * HDIM + ac;
    }
    u16* aDst = sA + ar * 40 + ac;

    const int kq2 = (tid >> 4) * 2, n4 = (tid & 15) * 4;
    const float* bSrcG = B + (size_t)e * 1024 * NB + (size_t)kq2 * NB + ct * 64 + n4;
    const float* bSrcU = bSrcG + 1024;

    const int lane = tid & 63, wave = tid >> 6;
    const int quad = lane >> 4, mr = lane & 15;

    const v4f zf = {0.f, 0.f, 0.f, 0.f};
    v4f accG[2][4], accU[2][4];
#pragma unroll
    for (int i = 0; i < 2; i++)
#pragma unroll
        for (int j = 0; j < 4; j++) { accG[i][j] = zf; accU[i][j] = zf; }

    for (int kk = 0; kk < HDIM / 32; kk++) {
        uint4 aw0 = make_uint4(0, 0, 0, 0), aw1 = make_uint4(0, 0, 0, 0);
        if (AF32) {
            if (aSrcF) {
                float4 f0 = *(const float4*)(aSrcF + kk * 32);
                float4 f1 = *(const float4*)(aSrcF + kk * 32 + 4);
                float4 f2 = *(const float4*)(aSrcF + kk * 32 + 8);
                float4 f3 = *(const float4*)(aSrcF + kk * 32 + 12);
                aw0 = make_uint4(pack2(f0.x, f0.y), pack2(f0.z, f0.w),
                                 pack2(f1.x, f1.y), pack2(f1.z, f1.w));
                aw1 = make_uint4(pack2(f2.x, f2.y), pack2(f2.z, f2.w),
                                 pack2(f3.x, f3.y), pack2(f3.z, f3.w));
            }
        } else {
            if (aSrcH) {
                aw0 = *(const uint4*)(aSrcH + kk * 32);
                aw1 = *(const uint4*)(aSrcH + kk * 32 + 8);
            }
        }
        const size_t bOff = (size_t)kk * 32 * NB;
        float4 g0 = *(const float4*)(bSrcG + bOff);
        float4 g1 = *(const float4*)(bSrcG + bOff + NB);
        float4 u0 = make_float4(0, 0, 0, 0), u1 = make_float4(0, 0, 0, 0);
        if (GATED) {
            u0 = *(const float4*)(bSrcU + bOff);
            u1 = *(const float4*)(bSrcU + bOff + NB);
        }

        __syncthreads();
        *(uint4*)aDst = aw0;
        *(uint4*)(aDst + 8) = aw1;
        {
            const float gx[4] = {g0.x, g0.y, g0.z, g0.w};
            const float gy[4] = {g1.x, g1.y, g1.z, g1.w};
#pragma unroll
            for (int j = 0; j < 4; j++)
                *(unsigned int*)&sB[(n4 + j) * 40 + kq2] = pack2(gx[j], gy[j]);
            if (GATED) {
                const float ux[4] = {u0.x, u0.y, u0.z, u0.w};
                const float uy[4] = {u1.x, u1.y, u1.z, u1.w};
#pragma unroll
                for (int j = 0; j < 4; j++)
                    *(unsigned int*)&sB[64 * 40 + (n4 + j) * 40 + kq2] = pack2(ux[j], uy[j]);
            }
        }
        __syncthreads();

        v8s af0 = *(const v8s*)(sA + (wave * 32 + mr) * 40 + quad * 8);
        v8s af1 = *(const v8s*)(sA + (wave * 32 + 16 + mr) * 40 + quad * 8);
#pragma unroll
        for (int nf = 0; nf < 4; nf++) {
            v8s bg = *(const v8s*)(sB + (nf * 16 + mr) * 40 + quad * 8);
            accG[0][nf] = __builtin_amdgcn_mfma_f32_16x16x32_bf16(af0, bg, accG[0][nf], 0, 0, 0);
            accG[1][nf] = __builtin_amdgcn_mfma_f32_16x16x32_bf16(af1, bg, accG[1][nf], 0, 0, 0);
            if (GATED) {
                v8s bu = *(const v8s*)(sB + 64 * 40 + (nf * 16 + mr) * 40 + quad * 8);
                accU[0][nf] = __builtin_amdgcn_mfma_f32_16x16x32_bf16(af0, bu, accU[0][nf], 0, 0, 0);
                accU[1][nf] = __builtin_amdgcn_mfma_f32_16x16x32_bf16(af1, bu, accU[1][nf], 0, 0, 0);
            }
        }
    }

#pragma unroll
    for (int mf = 0; mf < 2; mf++) {
#pragma unroll
        for (int reg = 0; reg < 4; reg++) {
            int rl = wave * 32 + mf * 16 + quad * 4 + reg;
            int grow = srid[rl];
            if (grow < 0) continue;
            size_t base = (size_t)grow * 1024 + ct * 64 + mr;
#pragma unroll
            for (int nf = 0; nf < 4; nf++) {
                float g = accG[mf][nf][reg];
                float val;
                if (GATED) {
                    float u = accU[mf][nf][reg];
                    val = (g / (1.0f + expf(-g))) * u;
                } else {
                    val = g;
                }
                C[base + nf * 16] = f2b(val);
            }
        }
    }
}

extern "C" void kernel_launch(void* const* d_in, const int* in_sizes, int n_in,
                              void* d_out, int out_size, void* d_ws, size_t ws_size,
                              hipStream_t stream) {
    const float *X = 0, *RL = 0, *WU = 0, *WD = 0;
    for (int i = 0; i < n_in; i++) {
        switch (in_sizes[i]) {
            case T_TOK * HDIM:        X  = (const float*)d_in[i]; break;
            case T_TOK * NEXP:        RL = (const float*)d_in[i]; break;
            case NEXP * HDIM * 2048:  WU = (const float*)d_in[i]; break;
            case NEXP * HDIM * 1024:  WD = (const float*)d_in[i]; break;
            default: break;
        }
    }
    if (!X)  X  = (const float*)d_in[0];
    if (!RL) RL = (const float*)d_in[1];
    if (!WU) WU = (const float*)d_in[2];
    if (!WD) WD = (const float*)d_in[3];
    float* OUT = (float*)d_out;

    char* ws = (char*)d_ws;
    int*   ids    = (int*)(ws + 0);
    float* wts    = (float*)(ws + 32768);
    int*   counts = (int*)(ws + 65536);
    int*   rowbuf = (int*)(ws + 65792);               // ends 196864
    u16* Xb   = (u16*)(ws + 196864);                  // 8 MB
    u16* WtU  = (u16*)(ws + 8585472);                 // 32 MB (dead after GEMM1)
    u16* WtD  = (u16*)(ws + 42139904);                // 16 MB
    u16* HbufF= (u16*)(ws + 58917120);                // 16 MB
    u16* AccF = WtU;                                  // 16 MB, aliases dead WtU
    const size_t needFast = 75694336ull;
    u16* Hbuf = (u16*)(ws + 196864);
    u16* Acc  = (u16*)(ws + 196864 + 16777216);

    hipMemsetAsync(counts, 0, NEXP * sizeof(int), stream);

    if (ws_size >= needFast) {
        prep_all<<<10256, 256, 0, stream>>>(
            X, RL, WU, WD, Xb, WtU, WtD, ids, wts, counts, rowbuf);
        mfma_gemm<1><<<4096, 256, 0, stream>>>(Xb, WtU, HbufF, counts, rowbuf);
        mfma_gemm<2><<<2048, 256, 0, stream>>>(HbufF, WtD, AccF, counts, rowbuf);
        combine_kernel<<<T_TOK, 256, 0, stream>>>(AccF, wts, OUT);
    } else {
        router_kernel<<<T_TOK / 256, 256, 0, stream>>>(RL, ids, wts);
        bucket_kernel<<<RROWS / 256, 256, 0, stream>>>(ids, counts, rowbuf);
        moe_gemm_kernel<1, 1><<<dim3(16, 32, NEXP), 256, 0, stream>>>(
            (const void*)X, WU, Hbuf, counts, rowbuf, 1, 2048);
        moe_gemm_kernel<0, 0><<<dim3(16, 32, NEXP), 256, 0, stream>>>(
            (const void*)Hbuf, WD, Acc, counts, rowbuf, 0, 1024);
        combine_kernel<<<T_TOK, 256, 0, stream>>>(Acc, wts, OUT);
    }
}